// Round 5
// baseline (1543.423 us; speedup 1.0000x reference)
//
#include <hip/hip_runtime.h>

// EncoderDecoderLSTM, round 5: R4 structure, launch_bounds (512,2) so the
// weight fragments stay in registers (R4's (512,4) capped VGPRs at 64 and
// spilled 227MB/dispatch to scratch). 512 blocks x 16 rows -> 2 blocks/CU.

#define TT  336
#define HZN 168
#define NT  512
#define ROWS 16

typedef short s8v __attribute__((ext_vector_type(8)));
typedef short s2v __attribute__((ext_vector_type(2)));
typedef float f4v __attribute__((ext_vector_type(4)));
typedef float f2v __attribute__((ext_vector_type(2)));

__device__ __forceinline__ float fexp(float v){
  return __builtin_amdgcn_exp2f(v * 1.44269504088896340736f);
}
__device__ __forceinline__ float sigm(float v){
  return __builtin_amdgcn_rcpf(1.0f + fexp(-v));
}
__device__ __forceinline__ float tanh_(float v){
  return 1.0f - 2.0f * __builtin_amdgcn_rcpf(1.0f + fexp(2.0f * v));
}

__device__ __forceinline__ short bf16rne(float f){
  unsigned u = __float_as_uint(f);
  return (short)((u + 0x7fffu + ((u >> 16) & 1u)) >> 16);
}
// f ~= hi + lo (both bf16, RNE)
__device__ __forceinline__ void splitRNE(float f, short& hi, short& lo){
  hi = bf16rne(f);
  float fhi = __uint_as_float(((unsigned)(unsigned short)hi) << 16);
  lo = bf16rne(f - fhi);
}

// 2-product: c += (ah + al) * bh   (h fp32-exact, W bf16)
__device__ __forceinline__ f4v mm2(s8v ah, s8v al, s8v bh, f4v c){
  c = __builtin_amdgcn_mfma_f32_16x16x32_bf16(ah, bh, c, 0, 0, 0);
  c = __builtin_amdgcn_mfma_f32_16x16x32_bf16(al, bh, c, 0, 0, 0);
  return c;
}

// A-fragment (8 bf16) from swizzled h LDS [16][64] shorts
__device__ __forceinline__ s8v ldA(const short* hb, int l, int kt){
  int row = l & 15;
  int gr  = kt*4 + (l >> 4);
  return *(const s8v*)(hb + row*64 + ((gr ^ (row & 7)) << 3));
}

// B-fragments (bf16-hi) of a [256][64] weight matrix for this wave's n-block
__device__ __forceinline__ void loadBh(const float* __restrict__ Wm, int nb, int l,
                                       s8v Bh[2][2]){
  #pragma unroll
  for (int nt=0; nt<2; nt++)
    #pragma unroll
    for (int kt=0; kt<2; kt++){
      int n  = nb + nt*16 + (l & 15);
      int k0 = kt*32 + ((l >> 4) << 3);
      const float* p = Wm + n*64 + k0;
      float4 q0 = *(const float4*)(p);
      float4 q1 = *(const float4*)(p + 4);
      s8v vh;
      vh[0]=bf16rne(q0.x); vh[1]=bf16rne(q0.y); vh[2]=bf16rne(q0.z); vh[3]=bf16rne(q0.w);
      vh[4]=bf16rne(q1.x); vh[5]=bf16rne(q1.y); vh[6]=bf16rne(q1.z); vh[7]=bf16rne(q1.w);
      Bh[nt][kt] = vh;
    }
}

// write accs into swizzled fp32 gate buffer [16][256]
__device__ __forceinline__ void stG(float* __restrict__ g, int l, int nb,
                                    const f4v acc[2]){
  #pragma unroll
  for (int nt=0; nt<2; nt++){
    int n = nb + nt*16 + (l & 15);
    #pragma unroll
    for (int r=0; r<4; r++){
      int row = ((l >> 4) << 2) + r;
      g[row*256 + (((n >> 2) ^ (row & 7)) << 2) + (n & 3)] = acc[nt][r];
    }
  }
}

// pointwise LSTM update for 2 (row,col) elements
template<bool USEX>
__device__ __forceinline__ f2v pointw(const float* __restrict__ g,
                                      const float* __restrict__ wxs, float xv,
                                      int prow, int pcol, f2v& cv){
  f2v gv[4];
  #pragma unroll
  for (int T=0; T<4; T++){
    int gr = T*16 + (pcol >> 2);
    gv[T] = *(const f2v*)(g + prow*256 + ((gr ^ (prow & 7)) << 2) + (pcol & 3));
  }
  f2v wv[4];
  if (USEX){
    #pragma unroll
    for (int T=0; T<4; T++)
      wv[T] = *(const f2v*)(wxs + T*64 + pcol);
  }
  f2v h;
  #pragma unroll
  for (int j=0; j<2; j++){
    float gi = gv[0][j], gf = gv[1][j], gg = gv[2][j], go = gv[3][j];
    if (USEX){
      gi = fmaf(wv[0][j], xv, gi); gf = fmaf(wv[1][j], xv, gf);
      gg = fmaf(wv[2][j], xv, gg); go = fmaf(wv[3][j], xv, go);
    }
    float I = sigm(gi), F = sigm(gf), G = tanh_(gg), O = sigm(go);
    float cn = fmaf(F, cv[j], I*G);
    cv[j] = cn;
    h[j] = O * tanh_(cn);
  }
  return h;
}

// store 2 h elements as bf16 hi/lo into swizzled h LDS
__device__ __forceinline__ void stH(short* hhi, short* hlo, int prow, int pcol, f2v h){
  s2v vh, vl;
  #pragma unroll
  for (int j=0; j<2; j++){
    short hi, lo; splitRNE(h[j], hi, lo);
    vh[j] = hi; vl[j] = lo;
  }
  int idx = prow*64 + (((pcol >> 3) ^ (prow & 7)) << 3) + (pcol & 7);
  *(s2v*)(hhi + idx) = vh;
  *(s2v*)(hlo + idx) = vl;
}

__global__ __launch_bounds__(NT, 2)
void edlstm_kernel(const float* __restrict__ x,
  const float* __restrict__ eWih0, const float* __restrict__ eWhh0,
  const float* __restrict__ ebih0, const float* __restrict__ ebhh0,
  const float* __restrict__ eWih1, const float* __restrict__ eWhh1,
  const float* __restrict__ ebih1, const float* __restrict__ ebhh1,
  const float* __restrict__ dWih0, const float* __restrict__ dWhh0,
  const float* __restrict__ dbih0, const float* __restrict__ dbhh0,
  const float* __restrict__ dWih1, const float* __restrict__ dWhh1,
  const float* __restrict__ dbih1, const float* __restrict__ dbhh1,
  const float* __restrict__ fcW, const float* __restrict__ fcb,
  float* __restrict__ out)
{
  __shared__ short h0hi[ROWS*64], h0lo[ROWS*64], h1hi[ROWS*64], h1lo[ROWS*64];
  __shared__ float g0[ROWS*256], g1[ROWS*256];
  __shared__ float xs[ROWS*TT];
  __shared__ float wxs[256];

  const int tid  = threadIdx.x;
  const int l    = tid & 63;
  const int w    = tid >> 6;
  const int nb   = w * 32;            // wave's gate-row block base (0..224)
  const int prow = tid >> 5;          // pointwise row 0..15
  const int pcol = (tid & 31) * 2;    // pointwise col base (even)
  const int brow0 = blockIdx.x * ROWS;

  // ---- prologue ----
  { // zero h buffers (4 x 1024 shorts = 2048 dwords, contiguous)
    int* hz = (int*)h0hi;
    #pragma unroll
    for (int k=0; k<4; k++) hz[k*NT + tid] = 0;
  }
  #pragma unroll
  for (int k=0; k<3; k++){            // stage x: 16 rows x 84 float4
    int idx = k*NT + tid;
    if (idx < ROWS*84){
      int row = idx / 84;
      int c   = idx - row*84;
      *(float4*)(xs + row*TT + c*4) =
        *(const float4*)(x + (size_t)(brow0+row)*TT + c*4);
    }
  }
  if (tid < 256) wxs[tid] = eWih0[tid];

  float bE0[2], bE1[2], bD0[2], bD1[2];
  #pragma unroll
  for (int nt=0; nt<2; nt++){
    int n = nb + nt*16 + (l & 15);
    bE0[nt] = ebih0[n] + ebhh0[n];
    bE1[nt] = ebih1[n] + ebhh1[n];
    bD0[nt] = dbih0[n] + dbhh0[n];
    bD1[nt] = dbih1[n] + dbhh1[n];
  }
  f2v fcw = *(const f2v*)(fcW + pcol);
  const float fcb0 = fcb[0];

  // encoder B-fragments
  s8v Bhh0[2][2], Bih1[2][2], Bhh1[2][2];
  loadBh(eWhh0, nb, l, Bhh0);
  loadBh(eWih1, nb, l, Bih1);
  loadBh(eWhh1, nb, l, Bhh1);

  f2v c0 = {0.f, 0.f}, c1 = {0.f, 0.f};
  __syncthreads();

  // ---------------- encoder: 336 steps ----------------
  for (int t=0; t<TT; t++){
    // L0: g0 = bias + Whh0 . h0old  (x-part added in pointwise)
    f4v acc[2];
    #pragma unroll
    for (int nt=0; nt<2; nt++) acc[nt] = f4v{bE0[nt],bE0[nt],bE0[nt],bE0[nt]};
    #pragma unroll
    for (int kt=0; kt<2; kt++){
      s8v ah = ldA(h0hi, l, kt);
      s8v al = ldA(h0lo, l, kt);
      #pragma unroll
      for (int nt=0; nt<2; nt++) acc[nt] = mm2(ah, al, Bhh0[nt][kt], acc[nt]);
    }
    stG(g0, l, nb, acc);
    __syncthreads();                               // bar1: g0 ready

    float xv = xs[prow*TT + t];
    f2v h0v = pointw<true>(g0, wxs, xv, prow, pcol, c0);
    stH(h0hi, h0lo, prow, pcol, h0v);
    __syncthreads();                               // bar2: h0new ready

    // L1: g1 = bias + Wih1 . h0new + Whh1 . h1old
    #pragma unroll
    for (int nt=0; nt<2; nt++) acc[nt] = f4v{bE1[nt],bE1[nt],bE1[nt],bE1[nt]};
    #pragma unroll
    for (int kt=0; kt<2; kt++){
      s8v a0h = ldA(h0hi, l, kt);
      s8v a0l = ldA(h0lo, l, kt);
      s8v a1h = ldA(h1hi, l, kt);
      s8v a1l = ldA(h1lo, l, kt);
      #pragma unroll
      for (int nt=0; nt<2; nt++){
        acc[nt] = mm2(a0h, a0l, Bih1[nt][kt], acc[nt]);
        acc[nt] = mm2(a1h, a1l, Bhh1[nt][kt], acc[nt]);
      }
    }
    stG(g1, l, nb, acc);
    __syncthreads();                               // bar3: g1 ready

    f2v h1v = pointw<false>(g1, wxs, 0.f, prow, pcol, c1);
    stH(h1hi, h1lo, prow, pcol, h1v);
    // no barrier: h1 next read (L1 of t+1) is >= 2 barriers away; g0/h0 disjoint
  }

  // decoder B-fragments
  s8v Dih0[2][2];
  loadBh(dWih0, nb, l, Dih0);
  loadBh(dWhh0, nb, l, Bhh0);
  loadBh(dWih1, nb, l, Bih1);
  loadBh(dWhh1, nb, l, Bhh1);

  // ---------------- decoder: 168 steps ----------------
  for (int s=0; s<HZN; s++){
    // L0: g0 = bias + Whh0 . h0old + (s>0) Wih0 . h1old
    f4v acc[2];
    #pragma unroll
    for (int nt=0; nt<2; nt++) acc[nt] = f4v{bD0[nt],bD0[nt],bD0[nt],bD0[nt]};
    #pragma unroll
    for (int kt=0; kt<2; kt++){
      s8v ah = ldA(h0hi, l, kt);
      s8v al = ldA(h0lo, l, kt);
      #pragma unroll
      for (int nt=0; nt<2; nt++) acc[nt] = mm2(ah, al, Bhh0[nt][kt], acc[nt]);
    }
    if (s > 0){
      #pragma unroll
      for (int kt=0; kt<2; kt++){
        s8v ah = ldA(h1hi, l, kt);
        s8v al = ldA(h1lo, l, kt);
        #pragma unroll
        for (int nt=0; nt<2; nt++) acc[nt] = mm2(ah, al, Dih0[nt][kt], acc[nt]);
      }
    }
    stG(g0, l, nb, acc);
    __syncthreads();                               // bar1

    f2v h0v = pointw<false>(g0, wxs, 0.f, prow, pcol, c0);
    stH(h0hi, h0lo, prow, pcol, h0v);
    __syncthreads();                               // bar2

    // L1: g1 = bias + Wih1 . h0new + Whh1 . h1old
    #pragma unroll
    for (int nt=0; nt<2; nt++) acc[nt] = f4v{bD1[nt],bD1[nt],bD1[nt],bD1[nt]};
    #pragma unroll
    for (int kt=0; kt<2; kt++){
      s8v a0h = ldA(h0hi, l, kt);
      s8v a0l = ldA(h0lo, l, kt);
      s8v a1h = ldA(h1hi, l, kt);
      s8v a1l = ldA(h1lo, l, kt);
      #pragma unroll
      for (int nt=0; nt<2; nt++){
        acc[nt] = mm2(a0h, a0l, Bih1[nt][kt], acc[nt]);
        acc[nt] = mm2(a1h, a1l, Bhh1[nt][kt], acc[nt]);
      }
    }
    stG(g1, l, nb, acc);
    __syncthreads();                               // bar3

    f2v h1v = pointw<false>(g1, wxs, 0.f, prow, pcol, c1);
    stH(h1hi, h1lo, prow, pcol, h1v);

    // fc: pred[row] = sum_col h1 * fcW + fcb   (reduce 32 lanes = 64 cols)
    float p = h1v[0]*fcw[0] + h1v[1]*fcw[1];
    p += __shfl_xor(p, 1);  p += __shfl_xor(p, 2);
    p += __shfl_xor(p, 4);  p += __shfl_xor(p, 8);
    p += __shfl_xor(p, 16);
    if ((tid & 31) == 0)
      out[(size_t)(brow0 + prow)*HZN + s] = p + fcb0;
    __syncthreads();                               // bar4: h1new before next L0 read
  }
}

extern "C" void kernel_launch(void* const* d_in, const int* in_sizes, int n_in,
                              void* d_out, int out_size, void* d_ws, size_t ws_size,
                              hipStream_t stream)
{
  (void)in_sizes; (void)n_in; (void)d_ws; (void)ws_size; (void)out_size;
  const float* x     = (const float*)d_in[0];
  const float* eWih0 = (const float*)d_in[1];
  const float* eWhh0 = (const float*)d_in[2];
  const float* ebih0 = (const float*)d_in[3];
  const float* ebhh0 = (const float*)d_in[4];
  const float* eWih1 = (const float*)d_in[5];
  const float* eWhh1 = (const float*)d_in[6];
  const float* ebih1 = (const float*)d_in[7];
  const float* ebhh1 = (const float*)d_in[8];
  const float* dWih0 = (const float*)d_in[9];
  const float* dWhh0 = (const float*)d_in[10];
  const float* dbih0 = (const float*)d_in[11];
  const float* dbhh0 = (const float*)d_in[12];
  const float* dWih1 = (const float*)d_in[13];
  const float* dWhh1 = (const float*)d_in[14];
  const float* dbih1 = (const float*)d_in[15];
  const float* dbhh1 = (const float*)d_in[16];
  const float* fcW   = (const float*)d_in[17];
  const float* fcb   = (const float*)d_in[18];
  float* out = (float*)d_out;

  edlstm_kernel<<<dim3(512), dim3(NT), 0, stream>>>(
      x, eWih0, eWhh0, ebih0, ebhh0, eWih1, eWhh1, ebih1, ebhh1,
      dWih0, dWhh0, dbih0, dbhh0, dWih1, dWhh1, dbih1, dbhh1,
      fcW, fcb, out);
}

// Round 6
// 1151.793 us; speedup vs baseline: 1.3400x; 1.3400x over previous
//
#include <hip/hip_runtime.h>

// EncoderDecoderLSTM, round 6.
// - launch_bounds(512,4): total regs (arch+agpr) <= 128 so 2 blocks/CU co-reside.
// - Register demand lowered: biases in LDS (broadcast f4v read at acc init).
// - MFMA operands swapped (A=W, B=h): C/D lane holds 4 CONSECUTIVE gate rows
//   for one batch col -> gate store = 2 x b128 into pad-260 buffer (was 8 b32).
// 512 blocks x 16 rows, 512 threads (8 waves), dynamic LDS 68096 B.

#define TT  336
#define HZN 168
#define NT  512
#define ROWS 16
#define GP  260   // padded gate-row stride (floats) per batch row

typedef short s8v __attribute__((ext_vector_type(8)));
typedef short s2v __attribute__((ext_vector_type(2)));
typedef float f4v __attribute__((ext_vector_type(4)));
typedef float f2v __attribute__((ext_vector_type(2)));

__device__ __forceinline__ float fexp(float v){
  return __builtin_amdgcn_exp2f(v * 1.44269504088896340736f);
}
__device__ __forceinline__ float sigm(float v){
  return __builtin_amdgcn_rcpf(1.0f + fexp(-v));
}
__device__ __forceinline__ float tanh_(float v){
  return 1.0f - 2.0f * __builtin_amdgcn_rcpf(1.0f + fexp(2.0f * v));
}

__device__ __forceinline__ short bf16rne(float f){
  unsigned u = __float_as_uint(f);
  return (short)((u + 0x7fffu + ((u >> 16) & 1u)) >> 16);
}
__device__ __forceinline__ void splitRNE(float f, short& hi, short& lo){
  hi = bf16rne(f);
  float fhi = __uint_as_float(((unsigned)(unsigned short)hi) << 16);
  lo = bf16rne(f - fhi);
}

// c += W * (h_hi + h_lo): A = weight fragment, B = h fragment (hi/lo bf16)
__device__ __forceinline__ f4v mmW(s8v w, s8v hh, s8v hl, f4v c){
  c = __builtin_amdgcn_mfma_f32_16x16x32_bf16(w, hh, c, 0, 0, 0);
  c = __builtin_amdgcn_mfma_f32_16x16x32_bf16(w, hl, c, 0, 0, 0);
  return c;
}

// B-fragment (h): lane l holds h[batch = l&15][k = kt*32 + (l>>4)*8 .. +8]
__device__ __forceinline__ s8v ldA(const short* hb, int l, int kt){
  int row = l & 15;
  int gr  = kt*4 + (l >> 4);
  return *(const s8v*)(hb + row*64 + ((gr ^ (row & 7)) << 3));
}

// A-fragments (bf16 weights) of a [256][64] matrix: rows nb..nb+32, 2 m-tiles
__device__ __forceinline__ void loadBh(const float* __restrict__ Wm, int nb, int l,
                                       s8v Bh[2][2]){
  #pragma unroll
  for (int mt=0; mt<2; mt++)
    #pragma unroll
    for (int kt=0; kt<2; kt++){
      int n  = nb + mt*16 + (l & 15);
      int k0 = kt*32 + ((l >> 4) << 3);
      const float* p = Wm + n*64 + k0;
      float4 q0 = *(const float4*)(p);
      float4 q1 = *(const float4*)(p + 4);
      s8v vh;
      vh[0]=bf16rne(q0.x); vh[1]=bf16rne(q0.y); vh[2]=bf16rne(q0.z); vh[3]=bf16rne(q0.w);
      vh[4]=bf16rne(q1.x); vh[5]=bf16rne(q1.y); vh[6]=bf16rne(q1.z); vh[7]=bf16rne(q1.w);
      Bh[mt][kt] = vh;
    }
}

// bias f4v for m-tile mt (broadcast read: all 16 lanes of a group same addr)
__device__ __forceinline__ f4v ldBias(const float* __restrict__ bt, int nb, int l, int mt){
  return *(const f4v*)(bt + nb + mt*16 + ((l >> 4) << 2));
}

// store gates: lane l holds 4 consecutive gate rows for batch col l&15
__device__ __forceinline__ void stG(float* __restrict__ g, int l, int nb,
                                    f4v a0, f4v a1){
  int base = (l & 15)*GP + nb + ((l >> 4) << 2);
  *(f4v*)(g + base)      = a0;
  *(f4v*)(g + base + 16) = a1;
}

// pointwise LSTM update for 2 (batch b, hidden col hc) elements
template<bool USEX>
__device__ __forceinline__ f2v pointw(const float* __restrict__ g,
                                      const float* __restrict__ wxs, float xv,
                                      int b, int hc, f2v& cv){
  f2v gv[4];
  #pragma unroll
  for (int T=0; T<4; T++)
    gv[T] = *(const f2v*)(g + b*GP + T*64 + hc);
  f2v wv[4];
  if (USEX){
    #pragma unroll
    for (int T=0; T<4; T++)
      wv[T] = *(const f2v*)(wxs + T*64 + hc);
  }
  f2v h;
  #pragma unroll
  for (int j=0; j<2; j++){
    float gi = gv[0][j], gf = gv[1][j], gg = gv[2][j], go = gv[3][j];
    if (USEX){
      gi = fmaf(wv[0][j], xv, gi); gf = fmaf(wv[1][j], xv, gf);
      gg = fmaf(wv[2][j], xv, gg); go = fmaf(wv[3][j], xv, go);
    }
    float I = sigm(gi), F = sigm(gf), G = tanh_(gg), O = sigm(go);
    float cn = fmaf(F, cv[j], I*G);
    cv[j] = cn;
    h[j] = O * tanh_(cn);
  }
  return h;
}

__device__ __forceinline__ void stH(short* hhi, short* hlo, int b, int hc, f2v h){
  s2v vh, vl;
  #pragma unroll
  for (int j=0; j<2; j++){
    short hi, lo; splitRNE(h[j], hi, lo);
    vh[j] = hi; vl[j] = lo;
  }
  int idx = b*64 + (((hc >> 3) ^ (b & 7)) << 3) + (hc & 7);
  *(s2v*)(hhi + idx) = vh;
  *(s2v*)(hlo + idx) = vl;
}

__global__ __launch_bounds__(NT, 4)
void edlstm_kernel(const float* __restrict__ x,
  const float* __restrict__ eWih0, const float* __restrict__ eWhh0,
  const float* __restrict__ ebih0, const float* __restrict__ ebhh0,
  const float* __restrict__ eWih1, const float* __restrict__ eWhh1,
  const float* __restrict__ ebih1, const float* __restrict__ ebhh1,
  const float* __restrict__ dWih0, const float* __restrict__ dWhh0,
  const float* __restrict__ dbih0, const float* __restrict__ dbhh0,
  const float* __restrict__ dWih1, const float* __restrict__ dWhh1,
  const float* __restrict__ dbih1, const float* __restrict__ dbhh1,
  const float* __restrict__ fcW, const float* __restrict__ fcb,
  float* __restrict__ out)
{
  extern __shared__ float sm[];
  float* g0   = sm;                 // [16][260]
  float* g1   = sm + 16*GP;         // [16][260]
  float* xs   = sm + 2*16*GP;       // [16][336]
  float* wxs  = xs + ROWS*TT;       // [256]
  float* bias = wxs + 256;          // [4][256]: E0,E1,D0,D1
  short* hb   = (short*)(bias + 4*256);
  short* h0hi = hb;                 // [16][64] swizzled
  short* h0lo = hb + 1024;
  short* h1hi = hb + 2048;
  short* h1lo = hb + 3072;

  const int tid = threadIdx.x;
  const int l   = tid & 63;
  const int w   = tid >> 6;
  const int nb  = w * 32;           // wave's gate-row base (0..224)
  const int pb  = tid >> 5;         // pointwise batch row 0..15
  const int hc  = (tid & 31) * 2;   // pointwise hidden col (even)
  const int brow0 = blockIdx.x * ROWS;

  // ---- prologue ----
  { // zero h buffers: 4096 shorts = 2048 dwords
    int* hz = (int*)hb;
    #pragma unroll
    for (int k=0; k<4; k++) hz[k*NT + tid] = 0;
  }
  #pragma unroll
  for (int k=0; k<3; k++){          // stage x: 16 rows x 84 float4
    int idx = k*NT + tid;
    if (idx < ROWS*84){
      int row = idx / 84;
      int c   = idx - row*84;
      *(float4*)(xs + row*TT + c*4) =
        *(const float4*)(x + (size_t)(brow0+row)*TT + c*4);
    }
  }
  if (tid < 256){
    wxs[tid] = eWih0[tid];
    bias[tid]       = ebih0[tid] + ebhh0[tid];
    bias[256 + tid] = ebih1[tid] + ebhh1[tid];
    bias[512 + tid] = dbih0[tid] + dbhh0[tid];
    bias[768 + tid] = dbih1[tid] + dbhh1[tid];
  }

  f2v fcw = *(const f2v*)(fcW + hc);
  const float fcb0 = fcb[0];

  // encoder weight fragments (bf16) in registers
  s8v Whh0[2][2], Wih1[2][2], Whh1[2][2];
  loadBh(eWhh0, nb, l, Whh0);
  loadBh(eWih1, nb, l, Wih1);
  loadBh(eWhh1, nb, l, Whh1);

  f2v c0 = {0.f, 0.f}, c1 = {0.f, 0.f};
  __syncthreads();

  // ---------------- encoder: 336 steps ----------------
  for (int t=0; t<TT; t++){
    // L0: g0 = bias + Whh0 . h0old  (x-part added in pointwise)
    f4v a0 = ldBias(bias, nb, l, 0);
    f4v a1 = ldBias(bias, nb, l, 1);
    #pragma unroll
    for (int kt=0; kt<2; kt++){
      s8v hh = ldA(h0hi, l, kt);
      s8v hl = ldA(h0lo, l, kt);
      a0 = mmW(Whh0[0][kt], hh, hl, a0);
      a1 = mmW(Whh0[1][kt], hh, hl, a1);
    }
    stG(g0, l, nb, a0, a1);
    __syncthreads();                               // bar1: g0 ready

    float xv = xs[pb*TT + t];
    f2v h0v = pointw<true>(g0, wxs, xv, pb, hc, c0);
    stH(h0hi, h0lo, pb, hc, h0v);
    __syncthreads();                               // bar2: h0new ready

    // L1: g1 = bias + Wih1 . h0new + Whh1 . h1old
    a0 = ldBias(bias + 256, nb, l, 0);
    a1 = ldBias(bias + 256, nb, l, 1);
    #pragma unroll
    for (int kt=0; kt<2; kt++){
      s8v b0h = ldA(h0hi, l, kt);
      s8v b0l = ldA(h0lo, l, kt);
      s8v b1h = ldA(h1hi, l, kt);
      s8v b1l = ldA(h1lo, l, kt);
      a0 = mmW(Wih1[0][kt], b0h, b0l, a0);
      a1 = mmW(Wih1[1][kt], b0h, b0l, a1);
      a0 = mmW(Whh1[0][kt], b1h, b1l, a0);
      a1 = mmW(Whh1[1][kt], b1h, b1l, a1);
    }
    stG(g1, l, nb, a0, a1);
    __syncthreads();                               // bar3: g1 ready

    f2v h1v = pointw<false>(g1, wxs, 0.f, pb, hc, c1);
    stH(h1hi, h1lo, pb, hc, h1v);
    // no barrier: next reader/writer of h1/g1 is >= 2 barriers away
  }

  // decoder weight fragments
  s8v Dih0[2][2];
  loadBh(dWih0, nb, l, Dih0);
  loadBh(dWhh0, nb, l, Whh0);
  loadBh(dWih1, nb, l, Wih1);
  loadBh(dWhh1, nb, l, Whh1);

  // ---------------- decoder: 168 steps ----------------
  for (int s=0; s<HZN; s++){
    // L0: g0 = bias + Whh0 . h0old + (s>0) Wih0 . h1old
    f4v a0 = ldBias(bias + 512, nb, l, 0);
    f4v a1 = ldBias(bias + 512, nb, l, 1);
    #pragma unroll
    for (int kt=0; kt<2; kt++){
      s8v hh = ldA(h0hi, l, kt);
      s8v hl = ldA(h0lo, l, kt);
      a0 = mmW(Whh0[0][kt], hh, hl, a0);
      a1 = mmW(Whh0[1][kt], hh, hl, a1);
    }
    if (s > 0){
      #pragma unroll
      for (int kt=0; kt<2; kt++){
        s8v hh = ldA(h1hi, l, kt);
        s8v hl = ldA(h1lo, l, kt);
        a0 = mmW(Dih0[0][kt], hh, hl, a0);
        a1 = mmW(Dih0[1][kt], hh, hl, a1);
      }
    }
    stG(g0, l, nb, a0, a1);
    __syncthreads();                               // bar1

    f2v h0v = pointw<false>(g0, wxs, 0.f, pb, hc, c0);
    stH(h0hi, h0lo, pb, hc, h0v);
    __syncthreads();                               // bar2

    // L1: g1 = bias + Wih1 . h0new + Whh1 . h1old
    a0 = ldBias(bias + 768, nb, l, 0);
    a1 = ldBias(bias + 768, nb, l, 1);
    #pragma unroll
    for (int kt=0; kt<2; kt++){
      s8v b0h = ldA(h0hi, l, kt);
      s8v b0l = ldA(h0lo, l, kt);
      s8v b1h = ldA(h1hi, l, kt);
      s8v b1l = ldA(h1lo, l, kt);
      a0 = mmW(Wih1[0][kt], b0h, b0l, a0);
      a1 = mmW(Wih1[1][kt], b0h, b0l, a1);
      a0 = mmW(Whh1[0][kt], b1h, b1l, a0);
      a1 = mmW(Whh1[1][kt], b1h, b1l, a1);
    }
    stG(g1, l, nb, a0, a1);
    __syncthreads();                               // bar3

    f2v h1v = pointw<false>(g1, wxs, 0.f, pb, hc, c1);
    stH(h1hi, h1lo, pb, hc, h1v);

    // fc: pred[b] = sum_hc h1 * fcW + fcb  (reduce 32 lanes = 64 cols)
    float p = h1v[0]*fcw[0] + h1v[1]*fcw[1];
    p += __shfl_xor(p, 1);  p += __shfl_xor(p, 2);
    p += __shfl_xor(p, 4);  p += __shfl_xor(p, 8);
    p += __shfl_xor(p, 16);
    if ((tid & 31) == 0)
      out[(size_t)(brow0 + pb)*HZN + s] = p + fcb0;
    __syncthreads();                               // bar4: h1new before next L0
  }
}

extern "C" void kernel_launch(void* const* d_in, const int* in_sizes, int n_in,
                              void* d_out, int out_size, void* d_ws, size_t ws_size,
                              hipStream_t stream)
{
  (void)in_sizes; (void)n_in; (void)d_ws; (void)ws_size; (void)out_size;
  const float* x     = (const float*)d_in[0];
  const float* eWih0 = (const float*)d_in[1];
  const float* eWhh0 = (const float*)d_in[2];
  const float* ebih0 = (const float*)d_in[3];
  const float* ebhh0 = (const float*)d_in[4];
  const float* eWih1 = (const float*)d_in[5];
  const float* eWhh1 = (const float*)d_in[6];
  const float* ebih1 = (const float*)d_in[7];
  const float* ebhh1 = (const float*)d_in[8];
  const float* dWih0 = (const float*)d_in[9];
  const float* dWhh0 = (const float*)d_in[10];
  const float* dbih0 = (const float*)d_in[11];
  const float* dbhh0 = (const float*)d_in[12];
  const float* dWih1 = (const float*)d_in[13];
  const float* dWhh1 = (const float*)d_in[14];
  const float* dbih1 = (const float*)d_in[15];
  const float* dbhh1 = (const float*)d_in[16];
  const float* fcW   = (const float*)d_in[17];
  const float* fcb   = (const float*)d_in[18];
  float* out = (float*)d_out;

  // LDS: g0,g1 (2*16*260) + xs (16*336) + wxs 256 + bias 1024 floats + 8192 B h
  const int lds_bytes = (2*16*GP + ROWS*TT + 256 + 4*256) * 4 + 4096*2;  // 68096
  hipFuncSetAttribute((const void*)edlstm_kernel,
                      hipFuncAttributeMaxDynamicSharedMemorySize, lds_bytes);
  edlstm_kernel<<<dim3(512), dim3(NT), lds_bytes, stream>>>(
      x, eWih0, eWhh0, ebih0, ebhh0, eWih1, eWhh1, ebih1, ebhh1,
      dWih0, dWhh0, dbih0, dbhh0, dWih1, dWhh1, dbih1, dbhh1,
      fcW, fcb, out);
}

// Round 7
// 1026.342 us; speedup vs baseline: 1.5038x; 1.1222x over previous
//
#include <hip/hip_runtime.h>

// EncoderDecoderLSTM, round 7: gates never leave registers.
// A(=W) fragment m-rows permuted so D lane regs = {i,f,g,o} of one
// (batch=l&15, col=w*8+2*(l>>4)+mt) element -> pointwise fused in-lane,
// c-state in-lane, h written as bf16 hi/lo pairs to double-buffered LDS.
// 2 barriers/step. 512 blocks x 16 rows x 512 threads, 2 blocks/CU.

#define TT  336
#define HZN 168
#define NT  512
#define ROWS 16
#define XP  340   // padded x row stride (floats): 340%32=20 -> 2-way banks

typedef short s8v __attribute__((ext_vector_type(8)));
typedef short s2v __attribute__((ext_vector_type(2)));
typedef float f4v __attribute__((ext_vector_type(4)));

__device__ __forceinline__ float fexp(float v){
  return __builtin_amdgcn_exp2f(v * 1.44269504088896340736f);
}
__device__ __forceinline__ float sigm(float v){
  return __builtin_amdgcn_rcpf(1.0f + fexp(-v));
}
__device__ __forceinline__ float tanh_(float v){
  return 1.0f - 2.0f * __builtin_amdgcn_rcpf(1.0f + fexp(2.0f * v));
}

__device__ __forceinline__ short bf16rne(float f){
  unsigned u = __float_as_uint(f);
  return (short)((u + 0x7fffu + ((u >> 16) & 1u)) >> 16);
}
__device__ __forceinline__ void splitRNE(float f, short& hi, short& lo){
  hi = bf16rne(f);
  float fhi = __uint_as_float(((unsigned)(unsigned short)hi) << 16);
  lo = bf16rne(f - fhi);
}

// c += W * (h_hi + h_lo)
__device__ __forceinline__ f4v mmW(s8v w, s8v hh, s8v hl, f4v c){
  c = __builtin_amdgcn_mfma_f32_16x16x32_bf16(w, hh, c, 0, 0, 0);
  c = __builtin_amdgcn_mfma_f32_16x16x32_bf16(w, hl, c, 0, 0, 0);
  return c;
}

// B operand (h): lane l holds h[batch=l&15][k=(l>>4)*8 + kt*32 .. +8]
__device__ __forceinline__ s8v ldH(const short* hb, int l, int kt){
  int b  = l & 15;
  int gr = kt*4 + (l >> 4);
  return *(const s8v*)(hb + b*64 + ((gr ^ (b & 7)) << 3));
}

// A operand (W) with permuted m-rows: mm -> row (mm&3)*64 + w*8 + 2*(mm>>2) + mt
__device__ __forceinline__ s8v ldW(const float* __restrict__ Wm, int w, int l,
                                   int mt, int kt){
  int mm   = l & 15;
  int grow = (mm & 3)*64 + w*8 + 2*(mm >> 2) + mt;
  int k0   = kt*32 + (l >> 4)*8;
  const float* p = Wm + grow*64 + k0;
  float4 q0 = *(const float4*)(p);
  float4 q1 = *(const float4*)(p + 4);
  s8v v;
  v[0]=bf16rne(q0.x); v[1]=bf16rne(q0.y); v[2]=bf16rne(q0.z); v[3]=bf16rne(q0.w);
  v[4]=bf16rne(q1.x); v[5]=bf16rne(q1.y); v[6]=bf16rne(q1.z); v[7]=bf16rne(q1.w);
  return v;
}

// 4-gate column vector {i,f,g,o} at hidden col c from two bias arrays
__device__ __forceinline__ f4v ldBias2(const float* __restrict__ a,
                                       const float* __restrict__ bb, int c){
  return f4v{a[c]+bb[c], a[64+c]+bb[64+c], a[128+c]+bb[128+c], a[192+c]+bb[192+c]};
}
__device__ __forceinline__ f4v ldCol4(const float* __restrict__ a, int c){
  return f4v{a[c], a[64+c], a[128+c], a[192+c]};
}

// fused LSTM pointwise for one element; acc = {i,f,g,o}
__device__ __forceinline__ float pwise(f4v a, float& c){
  float I = sigm(a[0]), F = sigm(a[1]), G = tanh_(a[2]), O = sigm(a[3]);
  c = fmaf(F, c, I*G);
  return O * tanh_(c);
}

// store lane's two adjacent h cols (c0 even, c0+1) as bf16 hi/lo
__device__ __forceinline__ void stH(short* hhi, short* hlo, int b, int c0,
                                    float hA, float hB){
  short ha, la, hb2, lb;
  splitRNE(hA, ha, la);
  splitRNE(hB, hb2, lb);
  int idx = b*64 + (((c0 >> 3) ^ (b & 7)) << 3) + (c0 & 7);
  *(s2v*)(hhi + idx) = s2v{ha, hb2};
  *(s2v*)(hlo + idx) = s2v{la, lb};
}

__global__ __launch_bounds__(NT, 4)
void edlstm_kernel(const float* __restrict__ x,
  const float* __restrict__ eWih0, const float* __restrict__ eWhh0,
  const float* __restrict__ ebih0, const float* __restrict__ ebhh0,
  const float* __restrict__ eWih1, const float* __restrict__ eWhh1,
  const float* __restrict__ ebih1, const float* __restrict__ ebhh1,
  const float* __restrict__ dWih0, const float* __restrict__ dWhh0,
  const float* __restrict__ dbih0, const float* __restrict__ dbhh0,
  const float* __restrict__ dWih1, const float* __restrict__ dWhh1,
  const float* __restrict__ dbih1, const float* __restrict__ dbhh1,
  const float* __restrict__ fcW, const float* __restrict__ fcb,
  float* __restrict__ out)
{
  __shared__ float xs[ROWS*XP];     // 21760 B
  __shared__ short hS[16384];       // h0hi[2][2048] h0lo[2][2048] h1hi[2] h1lo[2]
  __shared__ float fcred[16*9];

  const int tid = threadIdx.x;
  const int l   = tid & 63;
  const int w   = tid >> 6;
  const int b   = l & 15;            // this lane's batch row
  const int c0  = w*8 + 2*(l >> 4);  // this lane's even hidden col
  const int c1  = c0 + 1;
  const int brow0 = blockIdx.x * ROWS;

  // ---- prologue ----
  { // zero all h buffers: 16384 shorts = 2048 int4
    int4* hz = (int4*)hS;
    #pragma unroll
    for (int k=0; k<4; k++) hz[k*NT + tid] = int4{0,0,0,0};
  }
  #pragma unroll
  for (int k=0; k<3; k++){           // stage x: 16 rows x 84 float4
    int idx = k*NT + tid;
    if (idx < ROWS*84){
      int row = idx / 84;
      int c   = idx - row*84;
      *(float4*)(xs + row*XP + c*4) =
        *(const float4*)(x + (size_t)(brow0+row)*TT + c*4);
    }
  }

  // per-lane constants (encoder)
  f4v bE0a = ldBias2(ebih0, ebhh0, c0), bE0b = ldBias2(ebih0, ebhh0, c1);
  f4v bE1a = ldBias2(ebih1, ebhh1, c0), bE1b = ldBias2(ebih1, ebhh1, c1);
  f4v wxa  = ldCol4(eWih0, c0),         wxb  = ldCol4(eWih0, c1);

  s8v Whh0[2][2], Wih1[2][2], Whh1[2][2];
  #pragma unroll
  for (int mt=0; mt<2; mt++)
    #pragma unroll
    for (int kt=0; kt<2; kt++){
      Whh0[mt][kt] = ldW(eWhh0, w, l, mt, kt);
      Wih1[mt][kt] = ldW(eWih1, w, l, mt, kt);
      Whh1[mt][kt] = ldW(eWhh1, w, l, mt, kt);
    }

  float cL0a = 0.f, cL0b = 0.f, cL1a = 0.f, cL1b = 0.f;
  int p = 0;
  __syncthreads();

  // ---------------- encoder: 336 steps, 2 barriers each ----------------
  for (int t=0; t<TT; t++){
    short* h0hR = hS          + p*2048;
    short* h0lR = hS + 4096   + p*2048;
    short* h0hW = hS          + (p^1)*2048;
    short* h0lW = hS + 4096   + (p^1)*2048;
    short* h1hR = hS + 8192   + p*2048;
    short* h1lR = hS + 12288  + p*2048;
    short* h1hW = hS + 8192   + (p^1)*2048;
    short* h1lW = hS + 12288  + (p^1)*2048;

    // phase A: L0 gates in regs -> h0 update in-lane
    float xv = xs[b*XP + t];
    f4v aA = bE0a + wxa*xv;
    f4v aB = bE0b + wxb*xv;
    #pragma unroll
    for (int kt=0; kt<2; kt++){
      s8v hh = ldH(h0hR, l, kt), hl = ldH(h0lR, l, kt);
      aA = mmW(Whh0[0][kt], hh, hl, aA);
      aB = mmW(Whh0[1][kt], hh, hl, aB);
    }
    float h0a = pwise(aA, cL0a);
    float h0b = pwise(aB, cL0b);
    stH(h0hW, h0lW, b, c0, h0a, h0b);
    __syncthreads();                               // bar1: h0new ready

    // phase B: L1 gates -> h1 update in-lane
    aA = bE1a; aB = bE1b;
    #pragma unroll
    for (int kt=0; kt<2; kt++){
      s8v g0h = ldH(h0hW, l, kt), g0l = ldH(h0lW, l, kt);
      s8v g1h = ldH(h1hR, l, kt), g1l = ldH(h1lR, l, kt);
      aA = mmW(Wih1[0][kt], g0h, g0l, aA);
      aB = mmW(Wih1[1][kt], g0h, g0l, aB);
      aA = mmW(Whh1[0][kt], g1h, g1l, aA);
      aB = mmW(Whh1[1][kt], g1h, g1l, aB);
    }
    float h1a = pwise(aA, cL1a);
    float h1b = pwise(aB, cL1b);
    stH(h1hW, h1lW, b, c0, h1a, h1b);
    __syncthreads();                               // bar2: h1new ready
    p ^= 1;
  }

  // decoder constants (overwrite encoder ones)
  s8v Dih0[2][2];
  #pragma unroll
  for (int mt=0; mt<2; mt++)
    #pragma unroll
    for (int kt=0; kt<2; kt++){
      Dih0[mt][kt] = ldW(dWih0, w, l, mt, kt);
      Whh0[mt][kt] = ldW(dWhh0, w, l, mt, kt);
      Wih1[mt][kt] = ldW(dWih1, w, l, mt, kt);
      Whh1[mt][kt] = ldW(dWhh1, w, l, mt, kt);
    }
  bE0a = ldBias2(dbih0, dbhh0, c0); bE0b = ldBias2(dbih0, dbhh0, c1);
  bE1a = ldBias2(dbih1, dbhh1, c0); bE1b = ldBias2(dbih1, dbhh1, c1);
  const float fcwA = fcW[c0], fcwB = fcW[c1], fcb0 = fcb[0];

  // ---------------- decoder: 168 steps, 2 barriers each ----------------
  for (int s=0; s<HZN; s++){
    short* h0hR = hS          + p*2048;
    short* h0lR = hS + 4096   + p*2048;
    short* h0hW = hS          + (p^1)*2048;
    short* h0lW = hS + 4096   + (p^1)*2048;
    short* h1hR = hS + 8192   + p*2048;
    short* h1lR = hS + 12288  + p*2048;
    short* h1hW = hS + 8192   + (p^1)*2048;
    short* h1lW = hS + 12288  + (p^1)*2048;

    // phase A: L0 gates = b + Whh0.h0 + (s>0) Wih0.h1
    f4v aA = bE0a, aB = bE0b;
    #pragma unroll
    for (int kt=0; kt<2; kt++){
      s8v hh = ldH(h0hR, l, kt), hl = ldH(h0lR, l, kt);
      aA = mmW(Whh0[0][kt], hh, hl, aA);
      aB = mmW(Whh0[1][kt], hh, hl, aB);
    }
    if (s > 0){
      #pragma unroll
      for (int kt=0; kt<2; kt++){
        s8v hh = ldH(h1hR, l, kt), hl = ldH(h1lR, l, kt);
        aA = mmW(Dih0[0][kt], hh, hl, aA);
        aB = mmW(Dih0[1][kt], hh, hl, aB);
      }
    }
    float h0a = pwise(aA, cL0a);
    float h0b = pwise(aB, cL0b);
    stH(h0hW, h0lW, b, c0, h0a, h0b);
    __syncthreads();                               // bar1

    // phase B: L1 gates
    aA = bE1a; aB = bE1b;
    #pragma unroll
    for (int kt=0; kt<2; kt++){
      s8v g0h = ldH(h0hW, l, kt), g0l = ldH(h0lW, l, kt);
      s8v g1h = ldH(h1hR, l, kt), g1l = ldH(h1lR, l, kt);
      aA = mmW(Wih1[0][kt], g0h, g0l, aA);
      aB = mmW(Wih1[1][kt], g0h, g0l, aB);
      aA = mmW(Whh1[0][kt], g1h, g1l, aA);
      aB = mmW(Whh1[1][kt], g1h, g1l, aB);
    }
    float h1a = pwise(aA, cL1a);
    float h1b = pwise(aB, cL1b);
    stH(h1hW, h1lW, b, c0, h1a, h1b);

    // fc partial: this lane's 2 cols; reduce over the 4 lane-groups in-wave
    float pr = h1a*fcwA + h1b*fcwB;
    pr += __shfl_xor(pr, 16);
    pr += __shfl_xor(pr, 32);
    if (l < 16) fcred[l*9 + w] = pr;
    __syncthreads();                               // bar2: h1new + fcred ready

    if (tid < 16){
      float sm = fcb0;
      #pragma unroll
      for (int j=0; j<8; j++) sm += fcred[tid*9 + j];
      out[(size_t)(brow0 + tid)*HZN + s] = sm;
    }
    p ^= 1;
  }
}

extern "C" void kernel_launch(void* const* d_in, const int* in_sizes, int n_in,
                              void* d_out, int out_size, void* d_ws, size_t ws_size,
                              hipStream_t stream)
{
  (void)in_sizes; (void)n_in; (void)d_ws; (void)ws_size; (void)out_size;
  const float* x     = (const float*)d_in[0];
  const float* eWih0 = (const float*)d_in[1];
  const float* eWhh0 = (const float*)d_in[2];
  const float* ebih0 = (const float*)d_in[3];
  const float* ebhh0 = (const float*)d_in[4];
  const float* eWih1 = (const float*)d_in[5];
  const float* eWhh1 = (const float*)d_in[6];
  const float* ebih1 = (const float*)d_in[7];
  const float* ebhh1 = (const float*)d_in[8];
  const float* dWih0 = (const float*)d_in[9];
  const float* dWhh0 = (const float*)d_in[10];
  const float* dbih0 = (const float*)d_in[11];
  const float* dbhh0 = (const float*)d_in[12];
  const float* dWih1 = (const float*)d_in[13];
  const float* dWhh1 = (const float*)d_in[14];
  const float* dbih1 = (const float*)d_in[15];
  const float* dbhh1 = (const float*)d_in[16];
  const float* fcW   = (const float*)d_in[17];
  const float* fcb   = (const float*)d_in[18];
  float* out = (float*)d_out;

  edlstm_kernel<<<dim3(512), dim3(NT), 0, stream>>>(
      x, eWih0, eWhh0, ebih0, ebhh0, eWih1, eWhh1, ebih1, ebhh1,
      dWih0, dWhh0, dbih0, dbhh0, dWih1, dWhh1, dbih1, dbhh1,
      fcW, fcb, out);
}

// Round 8
// 788.106 us; speedup vs baseline: 1.9584x; 1.3023x over previous
//
#include <hip/hip_runtime.h>

// EncoderDecoderLSTM, round 8.
// R7 structure (gates in regs, fused pointwise in-lane, 2 barriers/step) plus:
//  - register diet: biases/wx in LDS (broadcast f4v reads) -> no spill at
//    launch_bounds(512,4) (R7 spilled 68MB/dispatch to scratch).
//  - h stored as single bf16 (hi/lo dropped): halves h DS reads and MFMA count.
// 512 blocks x 16 rows x 512 threads, 2 blocks/CU.

#define TT  336
#define HZN 168
#define NT  512
#define ROWS 16
#define XP  340   // padded x row stride (floats)

typedef short s8v __attribute__((ext_vector_type(8)));
typedef short s2v __attribute__((ext_vector_type(2)));
typedef float f4v __attribute__((ext_vector_type(4)));

__device__ __forceinline__ float fexp(float v){
  return __builtin_amdgcn_exp2f(v * 1.44269504088896340736f);
}
__device__ __forceinline__ float sigm(float v){
  return __builtin_amdgcn_rcpf(1.0f + fexp(-v));
}
__device__ __forceinline__ float tanh_(float v){
  return 1.0f - 2.0f * __builtin_amdgcn_rcpf(1.0f + fexp(2.0f * v));
}

__device__ __forceinline__ short bf16rne(float f){
  unsigned u = __float_as_uint(f);
  return (short)((u + 0x7fffu + ((u >> 16) & 1u)) >> 16);
}

// B operand (h): lane l holds h[batch=l&15][k=(l>>4)*8 + kt*32 .. +8]
__device__ __forceinline__ s8v ldH(const short* hb, int l, int kt){
  int b  = l & 15;
  int gr = kt*4 + (l >> 4);
  return *(const s8v*)(hb + b*64 + ((gr ^ (b & 7)) << 3));
}

// A operand (W) with permuted m-rows: mm -> row (mm&3)*64 + w*8 + 2*(mm>>2) + mt
__device__ __forceinline__ s8v ldW(const float* __restrict__ Wm, int w, int l,
                                   int mt, int kt){
  int mm   = l & 15;
  int grow = (mm & 3)*64 + w*8 + 2*(mm >> 2) + mt;
  int k0   = kt*32 + (l >> 4)*8;
  const float* p = Wm + grow*64 + k0;
  float4 q0 = *(const float4*)(p);
  float4 q1 = *(const float4*)(p + 4);
  s8v v;
  v[0]=bf16rne(q0.x); v[1]=bf16rne(q0.y); v[2]=bf16rne(q0.z); v[3]=bf16rne(q0.w);
  v[4]=bf16rne(q1.x); v[5]=bf16rne(q1.y); v[6]=bf16rne(q1.z); v[7]=bf16rne(q1.w);
  return v;
}

// fused LSTM pointwise for one element; acc = {i,f,g,o}
__device__ __forceinline__ float pwise(f4v a, float& c){
  float I = sigm(a[0]), F = sigm(a[1]), G = tanh_(a[2]), O = sigm(a[3]);
  c = fmaf(F, c, I*G);
  return O * tanh_(c);
}

// store lane's two adjacent h cols (c0 even) as bf16
__device__ __forceinline__ void stH(short* hb, int b, int c0, float hA, float hB){
  int idx = b*64 + (((c0 >> 3) ^ (b & 7)) << 3) + (c0 & 7);
  *(s2v*)(hb + idx) = s2v{bf16rne(hA), bf16rne(hB)};
}

__global__ __launch_bounds__(NT, 4)
void edlstm_kernel(const float* __restrict__ x,
  const float* __restrict__ eWih0, const float* __restrict__ eWhh0,
  const float* __restrict__ ebih0, const float* __restrict__ ebhh0,
  const float* __restrict__ eWih1, const float* __restrict__ eWhh1,
  const float* __restrict__ ebih1, const float* __restrict__ ebhh1,
  const float* __restrict__ dWih0, const float* __restrict__ dWhh0,
  const float* __restrict__ dbih0, const float* __restrict__ dbhh0,
  const float* __restrict__ dWih1, const float* __restrict__ dWhh1,
  const float* __restrict__ dbih1, const float* __restrict__ dbhh1,
  const float* __restrict__ fcW, const float* __restrict__ fcb,
  float* __restrict__ out)
{
  __shared__ float xs[ROWS*XP];      // 21760 B
  __shared__ short hS[8192];         // h0[2][2048], h1[2][2048] bf16 swizzled
  __shared__ float fcred[16*9];
  __shared__ float bE0L[256], bE1L[256], bD0L[256], bD1L[256], wxL[256];

  const int tid = threadIdx.x;
  const int l   = tid & 63;
  const int w   = tid >> 6;
  const int b   = l & 15;            // this lane's batch row
  const int c0  = w*8 + 2*(l >> 4);  // this lane's even hidden col
  const int brow0 = blockIdx.x * ROWS;

  // ---- prologue ----
  { // zero h buffers: 8192 shorts = 1024 int4
    int4* hz = (int4*)hS;
    #pragma unroll
    for (int k=0; k<2; k++) hz[k*NT + tid] = int4{0,0,0,0};
  }
  #pragma unroll
  for (int k=0; k<3; k++){           // stage x: 16 rows x 84 float4
    int idx = k*NT + tid;
    if (idx < ROWS*84){
      int row = idx / 84;
      int c   = idx - row*84;
      *(float4*)(xs + row*XP + c*4) =
        *(const float4*)(x + (size_t)(brow0+row)*TT + c*4);
    }
  }
  if (tid < 256){                    // bias/wx tables: [col][gate] layout
    int c = tid >> 2, g = tid & 3;
    int j = g*64 + c;
    bE0L[tid] = ebih0[j] + ebhh0[j];
    bE1L[tid] = ebih1[j] + ebhh1[j];
    bD0L[tid] = dbih0[j] + dbhh0[j];
    bD1L[tid] = dbih1[j] + dbhh1[j];
    wxL[tid]  = eWih0[j];
  }

  // encoder weight fragments (bf16) in registers
  s8v Whh0[2][2], Wih1[2][2], Whh1[2][2];
  #pragma unroll
  for (int mt=0; mt<2; mt++)
    #pragma unroll
    for (int kt=0; kt<2; kt++){
      Whh0[mt][kt] = ldW(eWhh0, w, l, mt, kt);
      Wih1[mt][kt] = ldW(eWih1, w, l, mt, kt);
      Whh1[mt][kt] = ldW(eWhh1, w, l, mt, kt);
    }

  float cL0a = 0.f, cL0b = 0.f, cL1a = 0.f, cL1b = 0.f;
  int p = 0;
  __syncthreads();

  // ---------------- encoder: 336 steps, 2 barriers each ----------------
  for (int t=0; t<TT; t++){
    short* h0R = hS        + p*2048;
    short* h0W = hS        + (p^1)*2048;
    short* h1R = hS + 4096 + p*2048;
    short* h1W = hS + 4096 + (p^1)*2048;

    // phase A: L0 gates in regs -> h0 update in-lane
    float xv = xs[b*XP + t];
    f4v wxa = *(const f4v*)(wxL + c0*4);
    f4v wxb = *(const f4v*)(wxL + c0*4 + 4);
    f4v aA  = *(const f4v*)(bE0L + c0*4)     + wxa*xv;
    f4v aB  = *(const f4v*)(bE0L + c0*4 + 4) + wxb*xv;
    #pragma unroll
    for (int kt=0; kt<2; kt++){
      s8v hh = ldH(h0R, l, kt);
      aA = __builtin_amdgcn_mfma_f32_16x16x32_bf16(Whh0[0][kt], hh, aA, 0, 0, 0);
      aB = __builtin_amdgcn_mfma_f32_16x16x32_bf16(Whh0[1][kt], hh, aB, 0, 0, 0);
    }
    float h0a = pwise(aA, cL0a);
    float h0b = pwise(aB, cL0b);
    stH(h0W, b, c0, h0a, h0b);
    __syncthreads();                               // bar1: h0new ready

    // phase B: L1 gates -> h1 update in-lane
    aA = *(const f4v*)(bE1L + c0*4);
    aB = *(const f4v*)(bE1L + c0*4 + 4);
    #pragma unroll
    for (int kt=0; kt<2; kt++){
      s8v g0 = ldH(h0W, l, kt);
      s8v g1 = ldH(h1R, l, kt);
      aA = __builtin_amdgcn_mfma_f32_16x16x32_bf16(Wih1[0][kt], g0, aA, 0, 0, 0);
      aB = __builtin_amdgcn_mfma_f32_16x16x32_bf16(Wih1[1][kt], g0, aB, 0, 0, 0);
      aA = __builtin_amdgcn_mfma_f32_16x16x32_bf16(Whh1[0][kt], g1, aA, 0, 0, 0);
      aB = __builtin_amdgcn_mfma_f32_16x16x32_bf16(Whh1[1][kt], g1, aB, 0, 0, 0);
    }
    float h1a = pwise(aA, cL1a);
    float h1b = pwise(aB, cL1b);
    stH(h1W, b, c0, h1a, h1b);
    __syncthreads();                               // bar2: h1new ready
    p ^= 1;
  }

  // decoder weight fragments (overwrite + one extra set)
  s8v Dih0[2][2];
  #pragma unroll
  for (int mt=0; mt<2; mt++)
    #pragma unroll
    for (int kt=0; kt<2; kt++){
      Dih0[mt][kt] = ldW(dWih0, w, l, mt, kt);
      Whh0[mt][kt] = ldW(dWhh0, w, l, mt, kt);
      Wih1[mt][kt] = ldW(dWih1, w, l, mt, kt);
      Whh1[mt][kt] = ldW(dWhh1, w, l, mt, kt);
    }
  const float fcwA = fcW[c0], fcwB = fcW[c0+1], fcb0 = fcb[0];

  // ---------------- decoder: 168 steps, 2 barriers each ----------------
  for (int s=0; s<HZN; s++){
    short* h0R = hS        + p*2048;
    short* h0W = hS        + (p^1)*2048;
    short* h1R = hS + 4096 + p*2048;
    short* h1W = hS + 4096 + (p^1)*2048;

    // phase A: L0 gates = b + Whh0.h0 + (s>0) Wih0.h1
    f4v aA = *(const f4v*)(bD0L + c0*4);
    f4v aB = *(const f4v*)(bD0L + c0*4 + 4);
    #pragma unroll
    for (int kt=0; kt<2; kt++){
      s8v hh = ldH(h0R, l, kt);
      aA = __builtin_amdgcn_mfma_f32_16x16x32_bf16(Whh0[0][kt], hh, aA, 0, 0, 0);
      aB = __builtin_amdgcn_mfma_f32_16x16x32_bf16(Whh0[1][kt], hh, aB, 0, 0, 0);
    }
    if (s > 0){
      #pragma unroll
      for (int kt=0; kt<2; kt++){
        s8v hh = ldH(h1R, l, kt);
        aA = __builtin_amdgcn_mfma_f32_16x16x32_bf16(Dih0[0][kt], hh, aA, 0, 0, 0);
        aB = __builtin_amdgcn_mfma_f32_16x16x32_bf16(Dih0[1][kt], hh, aB, 0, 0, 0);
      }
    }
    float h0a = pwise(aA, cL0a);
    float h0b = pwise(aB, cL0b);
    stH(h0W, b, c0, h0a, h0b);
    __syncthreads();                               // bar1

    // phase B: L1 gates
    aA = *(const f4v*)(bD1L + c0*4);
    aB = *(const f4v*)(bD1L + c0*4 + 4);
    #pragma unroll
    for (int kt=0; kt<2; kt++){
      s8v g0 = ldH(h0W, l, kt);
      s8v g1 = ldH(h1R, l, kt);
      aA = __builtin_amdgcn_mfma_f32_16x16x32_bf16(Wih1[0][kt], g0, aA, 0, 0, 0);
      aB = __builtin_amdgcn_mfma_f32_16x16x32_bf16(Wih1[1][kt], g0, aB, 0, 0, 0);
      aA = __builtin_amdgcn_mfma_f32_16x16x32_bf16(Whh1[0][kt], g1, aA, 0, 0, 0);
      aB = __builtin_amdgcn_mfma_f32_16x16x32_bf16(Whh1[1][kt], g1, aB, 0, 0, 0);
    }
    float h1a = pwise(aA, cL1a);
    float h1b = pwise(aB, cL1b);
    stH(h1W, b, c0, h1a, h1b);

    // fc partial: this lane's 2 cols; reduce the 4 col-groups + cross-half
    float pr = h1a*fcwA + h1b*fcwB;
    pr += __shfl_xor(pr, 16);
    pr += __shfl_xor(pr, 32);
    if (l < 16) fcred[l*9 + w] = pr;
    __syncthreads();                               // bar2: h1new + fcred ready

    if (tid < 16){
      float sm = fcb0;
      #pragma unroll
      for (int j=0; j<8; j++) sm += fcred[tid*9 + j];
      out[(size_t)(brow0 + tid)*HZN + s] = sm;
    }
    p ^= 1;
  }
}

extern "C" void kernel_launch(void* const* d_in, const int* in_sizes, int n_in,
                              void* d_out, int out_size, void* d_ws, size_t ws_size,
                              hipStream_t stream)
{
  (void)in_sizes; (void)n_in; (void)d_ws; (void)ws_size; (void)out_size;
  const float* x     = (const float*)d_in[0];
  const float* eWih0 = (const float*)d_in[1];
  const float* eWhh0 = (const float*)d_in[2];
  const float* ebih0 = (const float*)d_in[3];
  const float* ebhh0 = (const float*)d_in[4];
  const float* eWih1 = (const float*)d_in[5];
  const float* eWhh1 = (const float*)d_in[6];
  const float* ebih1 = (const float*)d_in[7];
  const float* ebhh1 = (const float*)d_in[8];
  const float* dWih0 = (const float*)d_in[9];
  const float* dWhh0 = (const float*)d_in[10];
  const float* dbih0 = (const float*)d_in[11];
  const float* dbhh0 = (const float*)d_in[12];
  const float* dWih1 = (const float*)d_in[13];
  const float* dWhh1 = (const float*)d_in[14];
  const float* dbih1 = (const float*)d_in[15];
  const float* dbhh1 = (const float*)d_in[16];
  const float* fcW   = (const float*)d_in[17];
  const float* fcb   = (const float*)d_in[18];
  float* out = (float*)d_out;

  edlstm_kernel<<<dim3(512), dim3(NT), 0, stream>>>(
      x, eWih0, eWhh0, ebih0, ebhh0, eWih1, eWhh1, ebih1, ebhh1,
      dWih0, dWhh0, dbih0, dbhh0, dWih1, dWhh1, dbih1, dbhh1,
      fcW, fcb, out);
}

// Round 9
// 772.707 us; speedup vs baseline: 1.9974x; 1.0199x over previous
//
#include <hip/hip_runtime.h>

// EncoderDecoderLSTM, round 9.
// R8 + encoder superphase pipelining: L0(t+1) depends only on h0(t), so each
// encoder step does {L1(t) + L0(t+1)} with ONE barrier (was 2), reusing the
// h0(t) fragments for both Wih1 and Whh0 MFMAs. Loops unrolled x2 so all LDS
// addresses are static offsets. Decoder keeps 2 barriers (h1 dependency).
// 512 blocks x 16 rows x 512 threads, 2 blocks/CU.

#define TT  336
#define HZN 168
#define NT  512
#define ROWS 16
#define XP  340

typedef short s8v __attribute__((ext_vector_type(8)));
typedef short s2v __attribute__((ext_vector_type(2)));
typedef float f4v __attribute__((ext_vector_type(4)));

#define MF(wf, hf, c) __builtin_amdgcn_mfma_f32_16x16x32_bf16((wf), (hf), (c), 0, 0, 0)

__device__ __forceinline__ float fexp(float v){
  return __builtin_amdgcn_exp2f(v * 1.44269504088896340736f);
}
__device__ __forceinline__ float sigm(float v){
  return __builtin_amdgcn_rcpf(1.0f + fexp(-v));
}
__device__ __forceinline__ float tanh_(float v){
  return 1.0f - 2.0f * __builtin_amdgcn_rcpf(1.0f + fexp(2.0f * v));
}
__device__ __forceinline__ short bf16rne(float f){
  unsigned u = __float_as_uint(f);
  return (short)((u + 0x7fffu + ((u >> 16) & 1u)) >> 16);
}

// h fragment: lane l holds h[batch=l&15][k=(l>>4)*8 + kt*32 .. +8]
__device__ __forceinline__ s8v ldH(const short* hb, int l, int kt){
  int b  = l & 15;
  int gr = kt*4 + (l >> 4);
  return *(const s8v*)(hb + b*64 + ((gr ^ (b & 7)) << 3));
}

// W fragment with permuted m-rows: mm -> row (mm&3)*64 + w*8 + 2*(mm>>2) + mt
__device__ __forceinline__ s8v ldW(const float* __restrict__ Wm, int w, int l,
                                   int mt, int kt){
  int mm   = l & 15;
  int grow = (mm & 3)*64 + w*8 + 2*(mm >> 2) + mt;
  int k0   = kt*32 + (l >> 4)*8;
  const float* p = Wm + grow*64 + k0;
  float4 q0 = *(const float4*)(p);
  float4 q1 = *(const float4*)(p + 4);
  s8v v;
  v[0]=bf16rne(q0.x); v[1]=bf16rne(q0.y); v[2]=bf16rne(q0.z); v[3]=bf16rne(q0.w);
  v[4]=bf16rne(q1.x); v[5]=bf16rne(q1.y); v[6]=bf16rne(q1.z); v[7]=bf16rne(q1.w);
  return v;
}

__device__ __forceinline__ float pwise(f4v a, float& c){
  float I = sigm(a[0]), F = sigm(a[1]), G = tanh_(a[2]), O = sigm(a[3]);
  c = fmaf(F, c, I*G);
  return O * tanh_(c);
}

__device__ __forceinline__ void stH(short* hb, int b, int c0, float hA, float hB){
  int idx = b*64 + (((c0 >> 3) ^ (b & 7)) << 3) + (c0 & 7);
  *(s2v*)(hb + idx) = s2v{bf16rne(hA), bf16rne(hB)};
}

// ---- encoder superphase: L1(t) + (DO_L0 ? L0(t+1) : nothing), 1 barrier ----
#define ENC_SUPER(P, t, DO_L0) {                                            \
  const short* h0R = hS + (P)*2048;                                         \
  short*       h0Wr = hS + ((P)^1)*2048;                                    \
  const short* h1R = hS + 4096 + (P)*2048;                                  \
  short*       h1Wr = hS + 4096 + ((P)^1)*2048;                             \
  s8v g00 = ldH(h0R, l, 0), g01 = ldH(h0R, l, 1);                           \
  s8v g10 = ldH(h1R, l, 0), g11 = ldH(h1R, l, 1);                           \
  f4v aA = *(const f4v*)(bE1L + c0*4);                                      \
  f4v aB = *(const f4v*)(bE1L + c0*4 + 4);                                  \
  f4v aC, aD;                                                               \
  if (DO_L0){                                                               \
    float xv = xs[b*XP + (t) + 1];                                          \
    f4v wxa = *(const f4v*)(wxL + c0*4);                                    \
    f4v wxb = *(const f4v*)(wxL + c0*4 + 4);                                \
    aC = *(const f4v*)(bE0L + c0*4)     + wxa*xv;                           \
    aD = *(const f4v*)(bE0L + c0*4 + 4) + wxb*xv;                           \
  }                                                                         \
  aA = MF(Wih1[0][0], g00, aA); aB = MF(Wih1[1][0], g00, aB);               \
  aA = MF(Wih1[0][1], g01, aA); aB = MF(Wih1[1][1], g01, aB);               \
  aA = MF(Whh1[0][0], g10, aA); aB = MF(Whh1[1][0], g10, aB);               \
  aA = MF(Whh1[0][1], g11, aA); aB = MF(Whh1[1][1], g11, aB);               \
  if (DO_L0){                                                               \
    aC = MF(Whh0[0][0], g00, aC); aD = MF(Whh0[1][0], g00, aD);             \
    aC = MF(Whh0[0][1], g01, aC); aD = MF(Whh0[1][1], g01, aD);             \
  }                                                                         \
  float h1a = pwise(aA, cL1a), h1b = pwise(aB, cL1b);                       \
  stH(h1Wr, b, c0, h1a, h1b);                                               \
  if (DO_L0){                                                               \
    float h0a = pwise(aC, cL0a), h0b = pwise(aD, cL0b);                     \
    stH(h0Wr, b, c0, h0a, h0b);                                             \
  }                                                                         \
  __syncthreads();                                                          \
}

// ---- decoder step: 2 barriers ----
#define DEC_STEP(Q, s) {                                                    \
  const short* h0R = hS + (Q)*2048;                                         \
  short*       h0Wr = hS + ((Q)^1)*2048;                                    \
  const short* h1R = hS + 4096 + ((Q)^1)*2048;                              \
  short*       h1Wr = hS + 4096 + (Q)*2048;                                 \
  f4v aA = *(const f4v*)(bD0L + c0*4);                                      \
  f4v aB = *(const f4v*)(bD0L + c0*4 + 4);                                  \
  s8v f0 = ldH(h0R, l, 0), f1 = ldH(h0R, l, 1);                             \
  aA = MF(Whh0[0][0], f0, aA); aB = MF(Whh0[1][0], f0, aB);                 \
  aA = MF(Whh0[0][1], f1, aA); aB = MF(Whh0[1][1], f1, aB);                 \
  if ((s) > 0){                                                             \
    s8v e0 = ldH(h1R, l, 0), e1 = ldH(h1R, l, 1);                           \
    aA = MF(Dih0[0][0], e0, aA); aB = MF(Dih0[1][0], e0, aB);               \
    aA = MF(Dih0[0][1], e1, aA); aB = MF(Dih0[1][1], e1, aB);               \
  }                                                                         \
  float h0a = pwise(aA, cL0a), h0b = pwise(aB, cL0b);                       \
  stH(h0Wr, b, c0, h0a, h0b);                                               \
  __syncthreads();                                                          \
  aA = *(const f4v*)(bD1L + c0*4);                                          \
  aB = *(const f4v*)(bD1L + c0*4 + 4);                                      \
  s8v g0 = ldH(h0Wr, l, 0), g1 = ldH(h0Wr, l, 1);                           \
  s8v e0 = ldH(h1R, l, 0),  e1 = ldH(h1R, l, 1);                            \
  aA = MF(Wih1[0][0], g0, aA); aB = MF(Wih1[1][0], g0, aB);                 \
  aA = MF(Wih1[0][1], g1, aA); aB = MF(Wih1[1][1], g1, aB);                 \
  aA = MF(Whh1[0][0], e0, aA); aB = MF(Whh1[1][0], e0, aB);                 \
  aA = MF(Whh1[0][1], e1, aA); aB = MF(Whh1[1][1], e1, aB);                 \
  float h1a = pwise(aA, cL1a), h1b = pwise(aB, cL1b);                       \
  stH(h1Wr, b, c0, h1a, h1b);                                               \
  float pr = h1a*fcwA + h1b*fcwB;                                           \
  pr += __shfl_xor(pr, 16); pr += __shfl_xor(pr, 32);                       \
  if (l < 16) fcred[l*9 + w] = pr;                                          \
  __syncthreads();                                                          \
  if (tid < 16){                                                            \
    float sm2 = fcb0;                                                       \
    _Pragma("unroll")                                                       \
    for (int j=0; j<8; j++) sm2 += fcred[tid*9 + j];                        \
    out[(size_t)(brow0 + tid)*HZN + (s)] = sm2;                             \
  }                                                                         \
}

__global__ __launch_bounds__(NT, 4)
void edlstm_kernel(const float* __restrict__ x,
  const float* __restrict__ eWih0, const float* __restrict__ eWhh0,
  const float* __restrict__ ebih0, const float* __restrict__ ebhh0,
  const float* __restrict__ eWih1, const float* __restrict__ eWhh1,
  const float* __restrict__ ebih1, const float* __restrict__ ebhh1,
  const float* __restrict__ dWih0, const float* __restrict__ dWhh0,
  const float* __restrict__ dbih0, const float* __restrict__ dbhh0,
  const float* __restrict__ dWih1, const float* __restrict__ dWhh1,
  const float* __restrict__ dbih1, const float* __restrict__ dbhh1,
  const float* __restrict__ fcW, const float* __restrict__ fcb,
  float* __restrict__ out)
{
  __shared__ float xs[ROWS*XP];
  __shared__ short hS[8192];         // h0[2][2048], h1[2][2048] bf16 swizzled
  __shared__ float fcred[16*9];
  __shared__ float bE0L[256], bE1L[256], bD0L[256], bD1L[256], wxL[256];

  const int tid = threadIdx.x;
  const int l   = tid & 63;
  const int w   = tid >> 6;
  const int b   = l & 15;
  const int c0  = w*8 + 2*(l >> 4);
  const int brow0 = blockIdx.x * ROWS;

  { // zero h buffers
    int4* hz = (int4*)hS;
    #pragma unroll
    for (int k=0; k<2; k++) hz[k*NT + tid] = int4{0,0,0,0};
  }
  #pragma unroll
  for (int k=0; k<3; k++){           // stage x
    int idx = k*NT + tid;
    if (idx < ROWS*84){
      int row = idx / 84;
      int c   = idx - row*84;
      *(float4*)(xs + row*XP + c*4) =
        *(const float4*)(x + (size_t)(brow0+row)*TT + c*4);
    }
  }
  if (tid < 256){                    // bias/wx tables: [col][gate]
    int c = tid >> 2, g = tid & 3;
    int j = g*64 + c;
    bE0L[tid] = ebih0[j] + ebhh0[j];
    bE1L[tid] = ebih1[j] + ebhh1[j];
    bD0L[tid] = dbih0[j] + dbhh0[j];
    bD1L[tid] = dbih1[j] + dbhh1[j];
    wxL[tid]  = eWih0[j];
  }

  s8v Whh0[2][2], Wih1[2][2], Whh1[2][2];
  #pragma unroll
  for (int mt=0; mt<2; mt++)
    #pragma unroll
    for (int kt=0; kt<2; kt++){
      Whh0[mt][kt] = ldW(eWhh0, w, l, mt, kt);
      Wih1[mt][kt] = ldW(eWih1, w, l, mt, kt);
      Whh1[mt][kt] = ldW(eWhh1, w, l, mt, kt);
    }

  float cL0a = 0.f, cL0b = 0.f, cL1a = 0.f, cL1b = 0.f;
  __syncthreads();

  // ---- encoder prologue: L0(0) = bias + wx*x0 (h0(-1)=0) -> h0buf[1] ----
  {
    float xv = xs[b*XP];
    f4v wxa = *(const f4v*)(wxL + c0*4);
    f4v wxb = *(const f4v*)(wxL + c0*4 + 4);
    f4v aA  = *(const f4v*)(bE0L + c0*4)     + wxa*xv;
    f4v aB  = *(const f4v*)(bE0L + c0*4 + 4) + wxb*xv;
    float h0a = pwise(aA, cL0a), h0b = pwise(aB, cL0b);
    stH(hS + 2048, b, c0, h0a, h0b);
    __syncthreads();
  }

  // ---- encoder: 336 superphases (t = 0..335), 1 barrier each ----
  for (int k=0; k<167; k++){
    ENC_SUPER(1, 2*k,   1);
    ENC_SUPER(0, 2*k+1, 1);
  }
  ENC_SUPER(1, 334, 1);
  ENC_SUPER(0, 335, 0);
  // now: h0(335) in h0buf[0], h1(335) in h1buf[1]

  // ---- decoder weights ----
  s8v Dih0[2][2];
  #pragma unroll
  for (int mt=0; mt<2; mt++)
    #pragma unroll
    for (int kt=0; kt<2; kt++){
      Dih0[mt][kt] = ldW(dWih0, w, l, mt, kt);
      Whh0[mt][kt] = ldW(dWhh0, w, l, mt, kt);
      Wih1[mt][kt] = ldW(dWih1, w, l, mt, kt);
      Whh1[mt][kt] = ldW(dWhh1, w, l, mt, kt);
    }
  const float fcwA = fcW[c0], fcwB = fcW[c0+1], fcb0 = fcb[0];

  // ---- decoder: 168 steps ----
  for (int k=0; k<84; k++){
    DEC_STEP(0, 2*k);
    DEC_STEP(1, 2*k+1);
  }
}

extern "C" void kernel_launch(void* const* d_in, const int* in_sizes, int n_in,
                              void* d_out, int out_size, void* d_ws, size_t ws_size,
                              hipStream_t stream)
{
  (void)in_sizes; (void)n_in; (void)d_ws; (void)ws_size; (void)out_size;
  const float* x     = (const float*)d_in[0];
  const float* eWih0 = (const float*)d_in[1];
  const float* eWhh0 = (const float*)d_in[2];
  const float* ebih0 = (const float*)d_in[3];
  const float* ebhh0 = (const float*)d_in[4];
  const float* eWih1 = (const float*)d_in[5];
  const float* eWhh1 = (const float*)d_in[6];
  const float* ebih1 = (const float*)d_in[7];
  const float* ebhh1 = (const float*)d_in[8];
  const float* dWih0 = (const float*)d_in[9];
  const float* dWhh0 = (const float*)d_in[10];
  const float* dbih0 = (const float*)d_in[11];
  const float* dbhh0 = (const float*)d_in[12];
  const float* dWih1 = (const float*)d_in[13];
  const float* dWhh1 = (const float*)d_in[14];
  const float* dbih1 = (const float*)d_in[15];
  const float* dbhh1 = (const float*)d_in[16];
  const float* fcW   = (const float*)d_in[17];
  const float* fcb   = (const float*)d_in[18];
  float* out = (float*)d_out;

  edlstm_kernel<<<dim3(512), dim3(NT), 0, stream>>>(
      x, eWih0, eWhh0, ebih0, ebhh0, eWih1, eWhh1, ebih1, ebhh1,
      dWih0, dWhh0, dbih0, dbhh0, dWih1, dWhh1, dbih1, dbhh1,
      fcW, fcb, out);
}

// Round 10
// 735.370 us; speedup vs baseline: 2.0988x; 1.0508x over previous
//
#include <hip/hip_runtime.h>

// EncoderDecoderLSTM, round 10.
// R9 superphase encoder (1 barrier/step) with:
//  - de-spilled phase order: only 2 accumulators live at a time
//  - 8-trans pointwise (shared-rcp forms), was 10 trans/element
//  - v_cvt_pk_bf16_f32 for h stores (1 inst instead of 2 manual RNE converts)
// 512 blocks x 16 rows x 512 threads, 2 blocks/CU, launch_bounds(512,4).

#define TT  336
#define HZN 168
#define NT  512
#define ROWS 16
#define XP  340

typedef short s8v __attribute__((ext_vector_type(8)));
typedef float f4v __attribute__((ext_vector_type(4)));

#define MF(wf, hf, c) __builtin_amdgcn_mfma_f32_16x16x32_bf16((wf), (hf), (c), 0, 0, 0)

__device__ __forceinline__ float fexp(float v){
  return __builtin_amdgcn_exp2f(v * 1.44269504088896340736f);
}
__device__ __forceinline__ short bf16rne(float f){
  unsigned u = __float_as_uint(f);
  return (short)((u + 0x7fffu + ((u >> 16) & 1u)) >> 16);
}

// h fragment: lane l holds h[batch=l&15][k=(l>>4)*8 + kt*32 .. +8]
__device__ __forceinline__ s8v ldH(const short* hb, int l, int kt){
  int b  = l & 15;
  int gr = kt*4 + (l >> 4);
  return *(const s8v*)(hb + b*64 + ((gr ^ (b & 7)) << 3));
}

// W fragment with permuted m-rows: mm -> row (mm&3)*64 + w*8 + 2*(mm>>2) + mt
__device__ __forceinline__ s8v ldW(const float* __restrict__ Wm, int w, int l,
                                   int mt, int kt){
  int mm   = l & 15;
  int grow = (mm & 3)*64 + w*8 + 2*(mm >> 2) + mt;
  int k0   = kt*32 + (l >> 4)*8;
  const float* p = Wm + grow*64 + k0;
  float4 q0 = *(const float4*)(p);
  float4 q1 = *(const float4*)(p + 4);
  s8v v;
  v[0]=bf16rne(q0.x); v[1]=bf16rne(q0.y); v[2]=bf16rne(q0.z); v[3]=bf16rne(q0.w);
  v[4]=bf16rne(q1.x); v[5]=bf16rne(q1.y); v[6]=bf16rne(q1.z); v[7]=bf16rne(q1.w);
  return v;
}

// 8-trans pointwise for two elements: gates {i,f,g,o} in aA/aB.
// i*g   = (e^{2g}-1) * rcp((1+e^{-i})(1+e^{2g}))
// f*c   = c * rcp(1+e^{-f})
// o*th  = (e^{2c}-1) * rcp((1+e^{-o})(1+e^{2c}))
__device__ __forceinline__ void pwise2(f4v aA, f4v aB, float& cA, float& cB,
                                       float& hA, float& hB){
  float eiA = fexp(-aA[0]), efA = fexp(-aA[1]);
  float egA = fexp(2.f*aA[2]), eoA = fexp(-aA[3]);
  float igA = (egA-1.f) * __builtin_amdgcn_rcpf((1.f+eiA)*(1.f+egA));
  float cnA = fmaf(cA, __builtin_amdgcn_rcpf(1.f+efA), igA);
  float ecA = fexp(2.f*cnA);
  hA = (ecA-1.f) * __builtin_amdgcn_rcpf((1.f+eoA)*(1.f+ecA));
  cA = cnA;
  float eiB = fexp(-aB[0]), efB = fexp(-aB[1]);
  float egB = fexp(2.f*aB[2]), eoB = fexp(-aB[3]);
  float igB = (egB-1.f) * __builtin_amdgcn_rcpf((1.f+eiB)*(1.f+egB));
  float cnB = fmaf(cB, __builtin_amdgcn_rcpf(1.f+efB), igB);
  float ecB = fexp(2.f*cnB);
  hB = (ecB-1.f) * __builtin_amdgcn_rcpf((1.f+eoB)*(1.f+ecB));
  cB = cnB;
}

// store lane's two adjacent h cols via packed bf16 convert (1 inst)
__device__ __forceinline__ void stH2(short* hb, int b, int c0, float hA, float hB){
  unsigned pk;
  asm("v_cvt_pk_bf16_f32 %0, %1, %2" : "=v"(pk) : "v"(hA), "v"(hB));
  int idx = b*64 + (((c0 >> 3) ^ (b & 7)) << 3) + (c0 & 7);
  *(unsigned*)(hb + idx) = pk;
}

// ---- encoder superphase: L1(t) then (DO_L0 ? L0(t+1) : skip), 1 barrier ----
#define ENC_SUPER(P, t, DO_L0) {                                            \
  const short* h0R  = hS + (P)*2048;                                        \
  short*       h0Wr = hS + ((P)^1)*2048;                                    \
  const short* h1R  = hS + 4096 + (P)*2048;                                 \
  short*       h1Wr = hS + 4096 + ((P)^1)*2048;                             \
  s8v g00 = ldH(h0R, l, 0), g01 = ldH(h0R, l, 1);                           \
  /* L1 */                                                                  \
  {                                                                         \
    s8v g10 = ldH(h1R, l, 0), g11 = ldH(h1R, l, 1);                         \
    f4v aA = *(const f4v*)(bE1L + c0*4);                                    \
    f4v aB = *(const f4v*)(bE1L + c0*4 + 4);                                \
    aA = MF(Wih1[0][0], g00, aA); aB = MF(Wih1[1][0], g00, aB);             \
    aA = MF(Wih1[0][1], g01, aA); aB = MF(Wih1[1][1], g01, aB);             \
    aA = MF(Whh1[0][0], g10, aA); aB = MF(Whh1[1][0], g10, aB);             \
    aA = MF(Whh1[0][1], g11, aA); aB = MF(Whh1[1][1], g11, aB);             \
    float h1a, h1b;                                                         \
    pwise2(aA, aB, cL1a, cL1b, h1a, h1b);                                   \
    stH2(h1Wr, b, c0, h1a, h1b);                                            \
  }                                                                         \
  /* L0(t+1) */                                                             \
  if (DO_L0){                                                               \
    float xv = xs[b*XP + (t) + 1];                                          \
    f4v wxa = *(const f4v*)(wxL + c0*4);                                    \
    f4v wxb = *(const f4v*)(wxL + c0*4 + 4);                                \
    f4v aC = *(const f4v*)(bE0L + c0*4)     + wxa*xv;                       \
    f4v aD = *(const f4v*)(bE0L + c0*4 + 4) + wxb*xv;                       \
    aC = MF(Whh0[0][0], g00, aC); aD = MF(Whh0[1][0], g00, aD);             \
    aC = MF(Whh0[0][1], g01, aC); aD = MF(Whh0[1][1], g01, aD);             \
    float h0a, h0b;                                                         \
    pwise2(aC, aD, cL0a, cL0b, h0a, h0b);                                   \
    stH2(h0Wr, b, c0, h0a, h0b);                                            \
  }                                                                         \
  __syncthreads();                                                          \
}

// ---- decoder step: 2 barriers ----
#define DEC_STEP(Q, s) {                                                    \
  const short* h0R  = hS + (Q)*2048;                                        \
  short*       h0Wr = hS + ((Q)^1)*2048;                                    \
  const short* h1R  = hS + 4096 + ((Q)^1)*2048;                             \
  short*       h1Wr = hS + 4096 + (Q)*2048;                                 \
  {                                                                         \
    f4v aA = *(const f4v*)(bD0L + c0*4);                                    \
    f4v aB = *(const f4v*)(bD0L + c0*4 + 4);                                \
    s8v f0 = ldH(h0R, l, 0), f1 = ldH(h0R, l, 1);                           \
    aA = MF(Whh0[0][0], f0, aA); aB = MF(Whh0[1][0], f0, aB);               \
    aA = MF(Whh0[0][1], f1, aA); aB = MF(Whh0[1][1], f1, aB);               \
    if ((s) > 0){                                                           \
      s8v e0 = ldH(h1R, l, 0), e1 = ldH(h1R, l, 1);                         \
      aA = MF(Dih0[0][0], e0, aA); aB = MF(Dih0[1][0], e0, aB);             \
      aA = MF(Dih0[0][1], e1, aA); aB = MF(Dih0[1][1], e1, aB);             \
    }                                                                       \
    float h0a, h0b;                                                         \
    pwise2(aA, aB, cL0a, cL0b, h0a, h0b);                                   \
    stH2(h0Wr, b, c0, h0a, h0b);                                            \
  }                                                                         \
  __syncthreads();                                                          \
  {                                                                         \
    f4v aA = *(const f4v*)(bD1L + c0*4);                                    \
    f4v aB = *(const f4v*)(bD1L + c0*4 + 4);                                \
    s8v g0 = ldH(h0Wr, l, 0), g1 = ldH(h0Wr, l, 1);                         \
    s8v e0 = ldH(h1R, l, 0),  e1 = ldH(h1R, l, 1);                          \
    aA = MF(Wih1[0][0], g0, aA); aB = MF(Wih1[1][0], g0, aB);               \
    aA = MF(Wih1[0][1], g1, aA); aB = MF(Wih1[1][1], g1, aB);               \
    aA = MF(Whh1[0][0], e0, aA); aB = MF(Whh1[1][0], e0, aB);               \
    aA = MF(Whh1[0][1], e1, aA); aB = MF(Whh1[1][1], e1, aB);               \
    float h1a, h1b;                                                         \
    pwise2(aA, aB, cL1a, cL1b, h1a, h1b);                                   \
    stH2(h1Wr, b, c0, h1a, h1b);                                            \
    float pr = h1a*fcwA + h1b*fcwB;                                         \
    pr += __shfl_xor(pr, 16); pr += __shfl_xor(pr, 32);                     \
    if (l < 16) fcred[l*9 + w] = pr;                                        \
  }                                                                         \
  __syncthreads();                                                          \
  if (tid < 16){                                                            \
    float sm2 = fcb0;                                                       \
    _Pragma("unroll")                                                       \
    for (int j=0; j<8; j++) sm2 += fcred[tid*9 + j];                        \
    out[(size_t)(brow0 + tid)*HZN + (s)] = sm2;                             \
  }                                                                         \
}

__global__ __launch_bounds__(NT, 4)
void edlstm_kernel(const float* __restrict__ x,
  const float* __restrict__ eWih0, const float* __restrict__ eWhh0,
  const float* __restrict__ ebih0, const float* __restrict__ ebhh0,
  const float* __restrict__ eWih1, const float* __restrict__ eWhh1,
  const float* __restrict__ ebih1, const float* __restrict__ ebhh1,
  const float* __restrict__ dWih0, const float* __restrict__ dWhh0,
  const float* __restrict__ dbih0, const float* __restrict__ dbhh0,
  const float* __restrict__ dWih1, const float* __restrict__ dWhh1,
  const float* __restrict__ dbih1, const float* __restrict__ dbhh1,
  const float* __restrict__ fcW, const float* __restrict__ fcb,
  float* __restrict__ out)
{
  __shared__ float xs[ROWS*XP];
  __shared__ short hS[8192];         // h0[2][2048], h1[2][2048] bf16 swizzled
  __shared__ float fcred[16*9];
  __shared__ float bE0L[256], bE1L[256], bD0L[256], bD1L[256], wxL[256];

  const int tid = threadIdx.x;
  const int l   = tid & 63;
  const int w   = tid >> 6;
  const int b   = l & 15;
  const int c0  = w*8 + 2*(l >> 4);
  const int brow0 = blockIdx.x * ROWS;

  { // zero h buffers
    int4* hz = (int4*)hS;
    #pragma unroll
    for (int k=0; k<2; k++) hz[k*NT + tid] = int4{0,0,0,0};
  }
  #pragma unroll
  for (int k=0; k<3; k++){           // stage x
    int idx = k*NT + tid;
    if (idx < ROWS*84){
      int row = idx / 84;
      int c   = idx - row*84;
      *(float4*)(xs + row*XP + c*4) =
        *(const float4*)(x + (size_t)(brow0+row)*TT + c*4);
    }
  }
  if (tid < 256){                    // bias/wx tables: [col][gate]
    int c = tid >> 2, g = tid & 3;
    int j = g*64 + c;
    bE0L[tid] = ebih0[j] + ebhh0[j];
    bE1L[tid] = ebih1[j] + ebhh1[j];
    bD0L[tid] = dbih0[j] + dbhh0[j];
    bD1L[tid] = dbih1[j] + dbhh1[j];
    wxL[tid]  = eWih0[j];
  }

  s8v Whh0[2][2], Wih1[2][2], Whh1[2][2];
  #pragma unroll
  for (int mt=0; mt<2; mt++)
    #pragma unroll
    for (int kt=0; kt<2; kt++){
      Whh0[mt][kt] = ldW(eWhh0, w, l, mt, kt);
      Wih1[mt][kt] = ldW(eWih1, w, l, mt, kt);
      Whh1[mt][kt] = ldW(eWhh1, w, l, mt, kt);
    }

  float cL0a = 0.f, cL0b = 0.f, cL1a = 0.f, cL1b = 0.f;
  __syncthreads();

  // ---- encoder prologue: L0(0) = bias + wx*x0 (h0(-1)=0) -> h0buf[1] ----
  {
    float xv = xs[b*XP];
    f4v wxa = *(const f4v*)(wxL + c0*4);
    f4v wxb = *(const f4v*)(wxL + c0*4 + 4);
    f4v aA  = *(const f4v*)(bE0L + c0*4)     + wxa*xv;
    f4v aB  = *(const f4v*)(bE0L + c0*4 + 4) + wxb*xv;
    float h0a, h0b;
    pwise2(aA, aB, cL0a, cL0b, h0a, h0b);
    stH2(hS + 2048, b, c0, h0a, h0b);
    __syncthreads();
  }

  // ---- encoder: 336 superphases, 1 barrier each ----
  for (int k=0; k<167; k++){
    ENC_SUPER(1, 2*k,   1);
    ENC_SUPER(0, 2*k+1, 1);
  }
  ENC_SUPER(1, 334, 1);
  ENC_SUPER(0, 335, 0);
  // now: h0(335) in h0buf[0], h1(335) in h1buf[1]

  // ---- decoder weights ----
  s8v Dih0[2][2];
  #pragma unroll
  for (int mt=0; mt<2; mt++)
    #pragma unroll
    for (int kt=0; kt<2; kt++){
      Dih0[mt][kt] = ldW(dWih0, w, l, mt, kt);
      Whh0[mt][kt] = ldW(dWhh0, w, l, mt, kt);
      Wih1[mt][kt] = ldW(dWih1, w, l, mt, kt);
      Whh1[mt][kt] = ldW(dWhh1, w, l, mt, kt);
    }
  const float fcwA = fcW[c0], fcwB = fcW[c0+1], fcb0 = fcb[0];

  // ---- decoder: 168 steps ----
  for (int k=0; k<84; k++){
    DEC_STEP(0, 2*k);
    DEC_STEP(1, 2*k+1);
  }
}

extern "C" void kernel_launch(void* const* d_in, const int* in_sizes, int n_in,
                              void* d_out, int out_size, void* d_ws, size_t ws_size,
                              hipStream_t stream)
{
  (void)in_sizes; (void)n_in; (void)d_ws; (void)ws_size; (void)out_size;
  const float* x     = (const float*)d_in[0];
  const float* eWih0 = (const float*)d_in[1];
  const float* eWhh0 = (const float*)d_in[2];
  const float* ebih0 = (const float*)d_in[3];
  const float* ebhh0 = (const float*)d_in[4];
  const float* eWih1 = (const float*)d_in[5];
  const float* eWhh1 = (const float*)d_in[6];
  const float* ebih1 = (const float*)d_in[7];
  const float* ebhh1 = (const float*)d_in[8];
  const float* dWih0 = (const float*)d_in[9];
  const float* dWhh0 = (const float*)d_in[10];
  const float* dbih0 = (const float*)d_in[11];
  const float* dbhh0 = (const float*)d_in[12];
  const float* dWih1 = (const float*)d_in[13];
  const float* dWhh1 = (const float*)d_in[14];
  const float* dbih1 = (const float*)d_in[15];
  const float* dbhh1 = (const float*)d_in[16];
  const float* fcW   = (const float*)d_in[17];
  const float* fcb   = (const float*)d_in[18];
  float* out = (float*)d_out;

  edlstm_kernel<<<dim3(512), dim3(NT), 0, stream>>>(
      x, eWih0, eWhh0, ebih0, ebhh0, eWih1, eWhh1, ebih1, ebhh1,
      dWih0, dWhh0, dbih0, dbhh0, dWih1, dWhh1, dbih1, dbhh1,
      fcW, fcb, out);
}

// Round 11
// 711.406 us; speedup vs baseline: 2.1695x; 1.0337x over previous
//
#include <hip/hip_runtime.h>

// EncoderDecoderLSTM, round 11.
// R10 + register/addressing diet:
//  - ldH/stH swizzled lane offsets hoisted to loop-invariant registers
//  - encoder biases + wx live in VGPRs (no per-step LDS bias reads)
//  - decoder reuses h1 fragments across phase A -> B (loaded once per step)
// 512 blocks x 16 rows x 512 threads, 2 blocks/CU, launch_bounds(512,4).

#define TT  336
#define HZN 168
#define NT  512
#define ROWS 16
#define XP  340

typedef short s8v __attribute__((ext_vector_type(8)));
typedef float f4v __attribute__((ext_vector_type(4)));

#define MF(wf, hf, c) __builtin_amdgcn_mfma_f32_16x16x32_bf16((wf), (hf), (c), 0, 0, 0)

__device__ __forceinline__ float fexp(float v){
  return __builtin_amdgcn_exp2f(v * 1.44269504088896340736f);
}
__device__ __forceinline__ short bf16rne(float f){
  unsigned u = __float_as_uint(f);
  return (short)((u + 0x7fffu + ((u >> 16) & 1u)) >> 16);
}

// W fragment with permuted m-rows: mm -> row (mm&3)*64 + w*8 + 2*(mm>>2) + mt
__device__ __forceinline__ s8v ldW(const float* __restrict__ Wm, int w, int l,
                                   int mt, int kt){
  int mm   = l & 15;
  int grow = (mm & 3)*64 + w*8 + 2*(mm >> 2) + mt;
  int k0   = kt*32 + (l >> 4)*8;
  const float* p = Wm + grow*64 + k0;
  float4 q0 = *(const float4*)(p);
  float4 q1 = *(const float4*)(p + 4);
  s8v v;
  v[0]=bf16rne(q0.x); v[1]=bf16rne(q0.y); v[2]=bf16rne(q0.z); v[3]=bf16rne(q0.w);
  v[4]=bf16rne(q1.x); v[5]=bf16rne(q1.y); v[6]=bf16rne(q1.z); v[7]=bf16rne(q1.w);
  return v;
}

// 8-trans pointwise for two elements: gates {i,f,g,o} in aA/aB.
__device__ __forceinline__ void pwise2(f4v aA, f4v aB, float& cA, float& cB,
                                       float& hA, float& hB){
  float eiA = fexp(-aA[0]), efA = fexp(-aA[1]);
  float egA = fexp(2.f*aA[2]), eoA = fexp(-aA[3]);
  float igA = (egA-1.f) * __builtin_amdgcn_rcpf((1.f+eiA)*(1.f+egA));
  float cnA = fmaf(cA, __builtin_amdgcn_rcpf(1.f+efA), igA);
  float ecA = fexp(2.f*cnA);
  hA = (ecA-1.f) * __builtin_amdgcn_rcpf((1.f+eoA)*(1.f+ecA));
  cA = cnA;
  float eiB = fexp(-aB[0]), efB = fexp(-aB[1]);
  float egB = fexp(2.f*aB[2]), eoB = fexp(-aB[3]);
  float igB = (egB-1.f) * __builtin_amdgcn_rcpf((1.f+eiB)*(1.f+egB));
  float cnB = fmaf(cB, __builtin_amdgcn_rcpf(1.f+efB), igB);
  float ecB = fexp(2.f*cnB);
  hB = (ecB-1.f) * __builtin_amdgcn_rcpf((1.f+eoB)*(1.f+ecB));
  cB = cnB;
}

// packed bf16 store of lane's two adjacent h cols
__device__ __forceinline__ void stH2(short* dst, float hA, float hB){
  unsigned pk;
  asm("v_cvt_pk_bf16_f32 %0, %1, %2" : "=v"(pk) : "v"(hA), "v"(hB));
  *(unsigned*)dst = pk;
}

// ---- encoder superphase: L1(t) then (DO_L0 ? L0(t+1) : skip), 1 barrier ----
#define ENC_SUPER(P, t, DO_L0) {                                            \
  const short* h0R  = hS + (P)*2048;                                        \
  short*       h0Wr = hS + ((P)^1)*2048;                                    \
  const short* h1R  = hS + 4096 + (P)*2048;                                 \
  short*       h1Wr = hS + 4096 + ((P)^1)*2048;                             \
  s8v g00 = *(const s8v*)(h0R + lo0), g01 = *(const s8v*)(h0R + lo1);       \
  {                                                                         \
    s8v g10 = *(const s8v*)(h1R + lo0), g11 = *(const s8v*)(h1R + lo1);     \
    f4v aA = bE1a, aB = bE1b;                                               \
    aA = MF(Wih1[0][0], g00, aA); aB = MF(Wih1[1][0], g00, aB);             \
    aA = MF(Wih1[0][1], g01, aA); aB = MF(Wih1[1][1], g01, aB);             \
    aA = MF(Whh1[0][0], g10, aA); aB = MF(Whh1[1][0], g10, aB);             \
    aA = MF(Whh1[0][1], g11, aA); aB = MF(Whh1[1][1], g11, aB);             \
    float h1a, h1b;                                                         \
    pwise2(aA, aB, cL1a, cL1b, h1a, h1b);                                   \
    stH2(h1Wr + so, h1a, h1b);                                              \
  }                                                                         \
  if (DO_L0){                                                               \
    float xv = xs[b*XP + (t) + 1];                                          \
    f4v aC = bE0a + wxa*xv;                                                 \
    f4v aD = bE0b + wxb*xv;                                                 \
    aC = MF(Whh0[0][0], g00, aC); aD = MF(Whh0[1][0], g00, aD);             \
    aC = MF(Whh0[0][1], g01, aC); aD = MF(Whh0[1][1], g01, aD);             \
    float h0a, h0b;                                                         \
    pwise2(aC, aD, cL0a, cL0b, h0a, h0b);                                   \
    stH2(h0Wr + so, h0a, h0b);                                              \
  }                                                                         \
  __syncthreads();                                                          \
}

// ---- decoder step: 2 barriers; h1 fragments loaded once, reused in B ----
#define DEC_STEP(Q, s) {                                                    \
  const short* h0R  = hS + (Q)*2048;                                        \
  short*       h0Wr = hS + ((Q)^1)*2048;                                    \
  const short* h1R  = hS + 4096 + ((Q)^1)*2048;                             \
  short*       h1Wr = hS + 4096 + (Q)*2048;                                 \
  s8v e0 = *(const s8v*)(h1R + lo0), e1 = *(const s8v*)(h1R + lo1);         \
  {                                                                         \
    f4v aA = *(const f4v*)(bD0L + c0*4);                                    \
    f4v aB = *(const f4v*)(bD0L + c0*4 + 4);                                \
    s8v f0 = *(const s8v*)(h0R + lo0), f1 = *(const s8v*)(h0R + lo1);       \
    aA = MF(Whh0[0][0], f0, aA); aB = MF(Whh0[1][0], f0, aB);               \
    aA = MF(Whh0[0][1], f1, aA); aB = MF(Whh0[1][1], f1, aB);               \
    if ((s) > 0){                                                           \
      aA = MF(Dih0[0][0], e0, aA); aB = MF(Dih0[1][0], e0, aB);             \
      aA = MF(Dih0[0][1], e1, aA); aB = MF(Dih0[1][1], e1, aB);             \
    }                                                                       \
    float h0a, h0b;                                                         \
    pwise2(aA, aB, cL0a, cL0b, h0a, h0b);                                   \
    stH2(h0Wr + so, h0a, h0b);                                              \
  }                                                                         \
  __syncthreads();                                                          \
  {                                                                         \
    f4v aA = *(const f4v*)(bD1L + c0*4);                                    \
    f4v aB = *(const f4v*)(bD1L + c0*4 + 4);                                \
    s8v g0 = *(const s8v*)(h0Wr + lo0), g1 = *(const s8v*)(h0Wr + lo1);     \
    aA = MF(Wih1[0][0], g0, aA); aB = MF(Wih1[1][0], g0, aB);               \
    aA = MF(Wih1[0][1], g1, aA); aB = MF(Wih1[1][1], g1, aB);               \
    aA = MF(Whh1[0][0], e0, aA); aB = MF(Whh1[1][0], e0, aB);               \
    aA = MF(Whh1[0][1], e1, aA); aB = MF(Whh1[1][1], e1, aB);               \
    float h1a, h1b;                                                         \
    pwise2(aA, aB, cL1a, cL1b, h1a, h1b);                                   \
    stH2(h1Wr + so, h1a, h1b);                                              \
    float pr = h1a*fcwA + h1b*fcwB;                                         \
    pr += __shfl_xor(pr, 16); pr += __shfl_xor(pr, 32);                     \
    if (l < 16) fcred[l*9 + w] = pr;                                        \
  }                                                                         \
  __syncthreads();                                                          \
  if (tid < 16){                                                            \
    float sm2 = fcb0;                                                       \
    _Pragma("unroll")                                                       \
    for (int j=0; j<8; j++) sm2 += fcred[tid*9 + j];                        \
    out[(size_t)(brow0 + tid)*HZN + (s)] = sm2;                             \
  }                                                                         \
}

__global__ __launch_bounds__(NT, 4)
void edlstm_kernel(const float* __restrict__ x,
  const float* __restrict__ eWih0, const float* __restrict__ eWhh0,
  const float* __restrict__ ebih0, const float* __restrict__ ebhh0,
  const float* __restrict__ eWih1, const float* __restrict__ eWhh1,
  const float* __restrict__ ebih1, const float* __restrict__ ebhh1,
  const float* __restrict__ dWih0, const float* __restrict__ dWhh0,
  const float* __restrict__ dbih0, const float* __restrict__ dbhh0,
  const float* __restrict__ dWih1, const float* __restrict__ dWhh1,
  const float* __restrict__ dbih1, const float* __restrict__ dbhh1,
  const float* __restrict__ fcW, const float* __restrict__ fcb,
  float* __restrict__ out)
{
  __shared__ float xs[ROWS*XP];
  __shared__ short hS[8192];         // h0[2][2048], h1[2][2048] bf16 swizzled
  __shared__ float fcred[16*9];
  __shared__ float bD0L[256], bD1L[256];

  const int tid = threadIdx.x;
  const int l   = tid & 63;
  const int w   = tid >> 6;
  const int b   = l & 15;
  const int c0  = w*8 + 2*(l >> 4);
  const int brow0 = blockIdx.x * ROWS;

  // loop-invariant swizzled lane offsets (shorts)
  const int lo0 = b*64 + ((((l >> 4)    ) ^ (b & 7)) << 3);
  const int lo1 = b*64 + (((4 + (l >> 4)) ^ (b & 7)) << 3);
  const int so  = b*64 + (((c0 >> 3) ^ (b & 7)) << 3) + (c0 & 7);

  { // zero h buffers
    int4* hz = (int4*)hS;
    #pragma unroll
    for (int k=0; k<2; k++) hz[k*NT + tid] = int4{0,0,0,0};
  }
  #pragma unroll
  for (int k=0; k<3; k++){           // stage x
    int idx = k*NT + tid;
    if (idx < ROWS*84){
      int row = idx / 84;
      int c   = idx - row*84;
      *(float4*)(xs + row*XP + c*4) =
        *(const float4*)(x + (size_t)(brow0+row)*TT + c*4);
    }
  }
  if (tid < 256){                    // decoder bias tables: [col][gate]
    int c = tid >> 2, g = tid & 3;
    int j = g*64 + c;
    bD0L[tid] = dbih0[j] + dbhh0[j];
    bD1L[tid] = dbih1[j] + dbhh1[j];
  }

  // encoder biases + wx in registers
  f4v bE0a, bE0b, bE1a, bE1b, wxa, wxb;
  #pragma unroll
  for (int g2=0; g2<4; g2++){
    int j = g2*64 + c0;
    bE0a[g2] = ebih0[j]   + ebhh0[j];
    bE0b[g2] = ebih0[j+1] + ebhh0[j+1];
    bE1a[g2] = ebih1[j]   + ebhh1[j];
    bE1b[g2] = ebih1[j+1] + ebhh1[j+1];
    wxa[g2]  = eWih0[j];
    wxb[g2]  = eWih0[j+1];
  }

  s8v Whh0[2][2], Wih1[2][2], Whh1[2][2];
  #pragma unroll
  for (int mt=0; mt<2; mt++)
    #pragma unroll
    for (int kt=0; kt<2; kt++){
      Whh0[mt][kt] = ldW(eWhh0, w, l, mt, kt);
      Wih1[mt][kt] = ldW(eWih1, w, l, mt, kt);
      Whh1[mt][kt] = ldW(eWhh1, w, l, mt, kt);
    }

  float cL0a = 0.f, cL0b = 0.f, cL1a = 0.f, cL1b = 0.f;
  __syncthreads();

  // ---- encoder prologue: L0(0) = bias + wx*x0 (h0(-1)=0) -> h0buf[1] ----
  {
    float xv = xs[b*XP];
    f4v aA = bE0a + wxa*xv;
    f4v aB = bE0b + wxb*xv;
    float h0a, h0b;
    pwise2(aA, aB, cL0a, cL0b, h0a, h0b);
    stH2(hS + 2048 + so, h0a, h0b);
    __syncthreads();
  }

  // ---- encoder: 336 superphases, 1 barrier each ----
  for (int k=0; k<167; k++){
    ENC_SUPER(1, 2*k,   1);
    ENC_SUPER(0, 2*k+1, 1);
  }
  ENC_SUPER(1, 334, 1);
  ENC_SUPER(0, 335, 0);
  // now: h0(335) in h0buf[0], h1(335) in h1buf[1]

  // ---- decoder weights ----
  s8v Dih0[2][2];
  #pragma unroll
  for (int mt=0; mt<2; mt++)
    #pragma unroll
    for (int kt=0; kt<2; kt++){
      Dih0[mt][kt] = ldW(dWih0, w, l, mt, kt);
      Whh0[mt][kt] = ldW(dWhh0, w, l, mt, kt);
      Wih1[mt][kt] = ldW(dWih1, w, l, mt, kt);
      Whh1[mt][kt] = ldW(dWhh1, w, l, mt, kt);
    }
  const float fcwA = fcW[c0], fcwB = fcW[c0+1], fcb0 = fcb[0];

  // ---- decoder: 168 steps ----
  for (int k=0; k<84; k++){
    DEC_STEP(0, 2*k);
    DEC_STEP(1, 2*k+1);
  }
}

extern "C" void kernel_launch(void* const* d_in, const int* in_sizes, int n_in,
                              void* d_out, int out_size, void* d_ws, size_t ws_size,
                              hipStream_t stream)
{
  (void)in_sizes; (void)n_in; (void)d_ws; (void)ws_size; (void)out_size;
  const float* x     = (const float*)d_in[0];
  const float* eWih0 = (const float*)d_in[1];
  const float* eWhh0 = (const float*)d_in[2];
  const float* ebih0 = (const float*)d_in[3];
  const float* ebhh0 = (const float*)d_in[4];
  const float* eWih1 = (const float*)d_in[5];
  const float* eWhh1 = (const float*)d_in[6];
  const float* ebih1 = (const float*)d_in[7];
  const float* ebhh1 = (const float*)d_in[8];
  const float* dWih0 = (const float*)d_in[9];
  const float* dWhh0 = (const float*)d_in[10];
  const float* dbih0 = (const float*)d_in[11];
  const float* dbhh0 = (const float*)d_in[12];
  const float* dWih1 = (const float*)d_in[13];
  const float* dWhh1 = (const float*)d_in[14];
  const float* dbih1 = (const float*)d_in[15];
  const float* dbhh1 = (const float*)d_in[16];
  const float* fcW   = (const float*)d_in[17];
  const float* fcb   = (const float*)d_in[18];
  float* out = (float*)d_out;

  edlstm_kernel<<<dim3(512), dim3(NT), 0, stream>>>(
      x, eWih0, eWhh0, ebih0, ebhh0, eWih1, eWhh1, ebih1, ebhh1,
      dWih0, dWhh0, dbih0, dbhh0, dWih1, dWhh1, dbih1, dbhh1,
      fcW, fcb, out);
}

// Round 12
// 639.669 us; speedup vs baseline: 2.4128x; 1.1121x over previous
//
#include <hip/hip_runtime.h>

// EncoderDecoderLSTM, round 12.
// R11 structure + issue-stream diet:
//  - log2e pre-scaling: gate weights/biases scaled by log2(e) at load, so
//    every exp becomes a bare v_exp_f32 (no preceding v_mul).
//  - packed-f32 pointwise: pwise2 on float2 ext-vectors -> v_pk_*_f32,
//    halving the scalar VALU ops in the nonlinearity.
// 512 blocks x 16 rows x 512 threads, 2 blocks/CU, launch_bounds(512,4).

#define TT  336
#define HZN 168
#define NT  512
#define ROWS 16
#define XP  340
#define LN2E 1.44269504088896340736f
#define K2  2.88539008177792681472f   // 2*log2(e)

typedef short s8v __attribute__((ext_vector_type(8)));
typedef float f4v __attribute__((ext_vector_type(4)));
typedef float f2v __attribute__((ext_vector_type(2)));

#define MF(wf, hf, c) __builtin_amdgcn_mfma_f32_16x16x32_bf16((wf), (hf), (c), 0, 0, 0)

__device__ __forceinline__ short bf16rne(float f){
  unsigned u = __float_as_uint(f);
  return (short)((u + 0x7fffu + ((u >> 16) & 1u)) >> 16);
}

__device__ __forceinline__ f2v prcp(f2v d){
  return f2v{__builtin_amdgcn_rcpf(d.x), __builtin_amdgcn_rcpf(d.y)};
}
__device__ __forceinline__ f2v pexp2(f2v d){
  return f2v{__builtin_amdgcn_exp2f(d.x), __builtin_amdgcn_exp2f(d.y)};
}

// W fragment with permuted m-rows, PRE-SCALED by log2(e):
// mm -> row (mm&3)*64 + w*8 + 2*(mm>>2) + mt
__device__ __forceinline__ s8v ldW(const float* __restrict__ Wm, int w, int l,
                                   int mt, int kt){
  int mm   = l & 15;
  int grow = (mm & 3)*64 + w*8 + 2*(mm >> 2) + mt;
  int k0   = kt*32 + (l >> 4)*8;
  const float* p = Wm + grow*64 + k0;
  float4 q0 = *(const float4*)(p);
  float4 q1 = *(const float4*)(p + 4);
  s8v v;
  v[0]=bf16rne(q0.x*LN2E); v[1]=bf16rne(q0.y*LN2E);
  v[2]=bf16rne(q0.z*LN2E); v[3]=bf16rne(q0.w*LN2E);
  v[4]=bf16rne(q1.x*LN2E); v[5]=bf16rne(q1.y*LN2E);
  v[6]=bf16rne(q1.z*LN2E); v[7]=bf16rne(q1.w*LN2E);
  return v;
}

// packed pointwise for two elements; gates PRE-SCALED by log2(e).
// sig(a) = 1/(1+2^-a'), tanh(g) = (2^{2g'}-1)/(2^{2g'}+1)
__device__ __forceinline__ void pwise2(f4v aA, f4v aB, f2v& c2,
                                       float& hA, float& hB){
  f2v i2{aA[0], aB[0]}, f2{aA[1], aB[1]}, g2{aA[2], aB[2]}, o2{aA[3], aB[3]};
  f2v ei = pexp2(-i2);
  f2v ef = pexp2(-f2);
  f2v eg = pexp2(g2 + g2);
  f2v eo = pexp2(-o2);
  f2v ig = (eg - 1.f) * prcp((1.f + ei) * (1.f + eg));
  f2v cn = c2 * prcp(1.f + ef) + ig;
  f2v ec = pexp2(cn * K2);
  f2v h  = (ec - 1.f) * prcp((1.f + eo) * (1.f + ec));
  c2 = cn;
  hA = h.x; hB = h.y;
}

// packed bf16 store of lane's two adjacent h cols
__device__ __forceinline__ void stH2(short* dst, float hA, float hB){
  unsigned pk;
  asm("v_cvt_pk_bf16_f32 %0, %1, %2" : "=v"(pk) : "v"(hA), "v"(hB));
  *(unsigned*)dst = pk;
}

// ---- encoder superphase: L1(t) then (DO_L0 ? L0(t+1) : skip), 1 barrier ----
#define ENC_SUPER(P, t, DO_L0) {                                            \
  const short* h0R  = hS + (P)*2048;                                        \
  short*       h0Wr = hS + ((P)^1)*2048;                                    \
  const short* h1R  = hS + 4096 + (P)*2048;                                 \
  short*       h1Wr = hS + 4096 + ((P)^1)*2048;                             \
  s8v g00 = *(const s8v*)(h0R + lo0), g01 = *(const s8v*)(h0R + lo1);       \
  {                                                                         \
    s8v g10 = *(const s8v*)(h1R + lo0), g11 = *(const s8v*)(h1R + lo1);     \
    f4v aA = bE1a, aB = bE1b;                                               \
    aA = MF(Wih1[0][0], g00, aA); aB = MF(Wih1[1][0], g00, aB);             \
    aA = MF(Wih1[0][1], g01, aA); aB = MF(Wih1[1][1], g01, aB);             \
    aA = MF(Whh1[0][0], g10, aA); aB = MF(Whh1[1][0], g10, aB);             \
    aA = MF(Whh1[0][1], g11, aA); aB = MF(Whh1[1][1], g11, aB);             \
    float h1a, h1b;                                                         \
    pwise2(aA, aB, c1s, h1a, h1b);                                          \
    stH2(h1Wr + so, h1a, h1b);                                              \
  }                                                                         \
  if (DO_L0){                                                               \
    float xv = xs[b*XP + (t) + 1];                                          \
    f4v aC = bE0a + wxa*xv;                                                 \
    f4v aD = bE0b + wxb*xv;                                                 \
    aC = MF(Whh0[0][0], g00, aC); aD = MF(Whh0[1][0], g00, aD);             \
    aC = MF(Whh0[0][1], g01, aC); aD = MF(Whh0[1][1], g01, aD);             \
    float h0a, h0b;                                                         \
    pwise2(aC, aD, c0s, h0a, h0b);                                          \
    stH2(h0Wr + so, h0a, h0b);                                              \
  }                                                                         \
  __syncthreads();                                                          \
}

// ---- decoder step: 2 barriers; h1 fragments loaded once, reused in B ----
#define DEC_STEP(Q, s) {                                                    \
  const short* h0R  = hS + (Q)*2048;                                        \
  short*       h0Wr = hS + ((Q)^1)*2048;                                    \
  const short* h1R  = hS + 4096 + ((Q)^1)*2048;                             \
  short*       h1Wr = hS + 4096 + (Q)*2048;                                 \
  s8v e0 = *(const s8v*)(h1R + lo0), e1 = *(const s8v*)(h1R + lo1);         \
  {                                                                         \
    f4v aA = *(const f4v*)(bD0L + c0*4);                                    \
    f4v aB = *(const f4v*)(bD0L + c0*4 + 4);                                \
    s8v f0 = *(const s8v*)(h0R + lo0), f1 = *(const s8v*)(h0R + lo1);       \
    aA = MF(Whh0[0][0], f0, aA); aB = MF(Whh0[1][0], f0, aB);               \
    aA = MF(Whh0[0][1], f1, aA); aB = MF(Whh0[1][1], f1, aB);               \
    if ((s) > 0){                                                           \
      aA = MF(Dih0[0][0], e0, aA); aB = MF(Dih0[1][0], e0, aB);             \
      aA = MF(Dih0[0][1], e1, aA); aB = MF(Dih0[1][1], e1, aB);             \
    }                                                                       \
    float h0a, h0b;                                                         \
    pwise2(aA, aB, c0s, h0a, h0b);                                          \
    stH2(h0Wr + so, h0a, h0b);                                              \
  }                                                                         \
  __syncthreads();                                                          \
  {                                                                         \
    f4v aA = *(const f4v*)(bD1L + c0*4);                                    \
    f4v aB = *(const f4v*)(bD1L + c0*4 + 4);                                \
    s8v g0 = *(const s8v*)(h0Wr + lo0), g1 = *(const s8v*)(h0Wr + lo1);     \
    aA = MF(Wih1[0][0], g0, aA); aB = MF(Wih1[1][0], g0, aB);               \
    aA = MF(Wih1[0][1], g1, aA); aB = MF(Wih1[1][1], g1, aB);               \
    aA = MF(Whh1[0][0], e0, aA); aB = MF(Whh1[1][0], e0, aB);               \
    aA = MF(Whh1[0][1], e1, aA); aB = MF(Whh1[1][1], e1, aB);               \
    float h1a, h1b;                                                         \
    pwise2(aA, aB, c1s, h1a, h1b);                                          \
    stH2(h1Wr + so, h1a, h1b);                                              \
    float pr = h1a*fcwA + h1b*fcwB;                                         \
    pr += __shfl_xor(pr, 16); pr += __shfl_xor(pr, 32);                     \
    if (l < 16) fcred[l*9 + w] = pr;                                        \
  }                                                                         \
  __syncthreads();                                                          \
  if (tid < 16){                                                            \
    float sm2 = fcb0;                                                       \
    _Pragma("unroll")                                                       \
    for (int j=0; j<8; j++) sm2 += fcred[tid*9 + j];                        \
    out[(size_t)(brow0 + tid)*HZN + (s)] = sm2;                             \
  }                                                                         \
}

__global__ __launch_bounds__(NT, 4)
void edlstm_kernel(const float* __restrict__ x,
  const float* __restrict__ eWih0, const float* __restrict__ eWhh0,
  const float* __restrict__ ebih0, const float* __restrict__ ebhh0,
  const float* __restrict__ eWih1, const float* __restrict__ eWhh1,
  const float* __restrict__ ebih1, const float* __restrict__ ebhh1,
  const float* __restrict__ dWih0, const float* __restrict__ dWhh0,
  const float* __restrict__ dbih0, const float* __restrict__ dbhh0,
  const float* __restrict__ dWih1, const float* __restrict__ dWhh1,
  const float* __restrict__ dbih1, const float* __restrict__ dbhh1,
  const float* __restrict__ fcW, const float* __restrict__ fcb,
  float* __restrict__ out)
{
  __shared__ float xs[ROWS*XP];
  __shared__ short hS[8192];         // h0[2][2048], h1[2][2048] bf16 swizzled
  __shared__ float fcred[16*9];
  __shared__ float bD0L[256], bD1L[256];

  const int tid = threadIdx.x;
  const int l   = tid & 63;
  const int w   = tid >> 6;
  const int b   = l & 15;
  const int c0  = w*8 + 2*(l >> 4);
  const int brow0 = blockIdx.x * ROWS;

  // loop-invariant swizzled lane offsets (shorts)
  const int lo0 = b*64 + ((((l >> 4)    ) ^ (b & 7)) << 3);
  const int lo1 = b*64 + (((4 + (l >> 4)) ^ (b & 7)) << 3);
  const int so  = b*64 + (((c0 >> 3) ^ (b & 7)) << 3) + (c0 & 7);

  { // zero h buffers
    int4* hz = (int4*)hS;
    #pragma unroll
    for (int k=0; k<2; k++) hz[k*NT + tid] = int4{0,0,0,0};
  }
  #pragma unroll
  for (int k=0; k<3; k++){           // stage x
    int idx = k*NT + tid;
    if (idx < ROWS*84){
      int row = idx / 84;
      int c   = idx - row*84;
      *(float4*)(xs + row*XP + c*4) =
        *(const float4*)(x + (size_t)(brow0+row)*TT + c*4);
    }
  }
  if (tid < 256){                    // decoder bias tables, pre-scaled
    int c = tid >> 2, g = tid & 3;
    int j = g*64 + c;
    bD0L[tid] = (dbih0[j] + dbhh0[j]) * LN2E;
    bD1L[tid] = (dbih1[j] + dbhh1[j]) * LN2E;
  }

  // encoder biases + wx in registers, pre-scaled
  f4v bE0a, bE0b, bE1a, bE1b, wxa, wxb;
  #pragma unroll
  for (int g2=0; g2<4; g2++){
    int j = g2*64 + c0;
    bE0a[g2] = (ebih0[j]   + ebhh0[j])   * LN2E;
    bE0b[g2] = (ebih0[j+1] + ebhh0[j+1]) * LN2E;
    bE1a[g2] = (ebih1[j]   + ebhh1[j])   * LN2E;
    bE1b[g2] = (ebih1[j+1] + ebhh1[j+1]) * LN2E;
    wxa[g2]  = eWih0[j]   * LN2E;
    wxb[g2]  = eWih0[j+1] * LN2E;
  }

  s8v Whh0[2][2], Wih1[2][2], Whh1[2][2];
  #pragma unroll
  for (int mt=0; mt<2; mt++)
    #pragma unroll
    for (int kt=0; kt<2; kt++){
      Whh0[mt][kt] = ldW(eWhh0, w, l, mt, kt);
      Wih1[mt][kt] = ldW(eWih1, w, l, mt, kt);
      Whh1[mt][kt] = ldW(eWhh1, w, l, mt, kt);
    }

  f2v c0s = {0.f, 0.f}, c1s = {0.f, 0.f};
  __syncthreads();

  // ---- encoder prologue: L0(0) = bias + wx*x0 (h0(-1)=0) -> h0buf[1] ----
  {
    float xv = xs[b*XP];
    f4v aA = bE0a + wxa*xv;
    f4v aB = bE0b + wxb*xv;
    float h0a, h0b;
    pwise2(aA, aB, c0s, h0a, h0b);
    stH2(hS + 2048 + so, h0a, h0b);
    __syncthreads();
  }

  // ---- encoder: 336 superphases, 1 barrier each ----
  for (int k=0; k<167; k++){
    ENC_SUPER(1, 2*k,   1);
    ENC_SUPER(0, 2*k+1, 1);
  }
  ENC_SUPER(1, 334, 1);
  ENC_SUPER(0, 335, 0);
  // now: h0(335) in h0buf[0], h1(335) in h1buf[1]

  // ---- decoder weights ----
  s8v Dih0[2][2];
  #pragma unroll
  for (int mt=0; mt<2; mt++)
    #pragma unroll
    for (int kt=0; kt<2; kt++){
      Dih0[mt][kt] = ldW(dWih0, w, l, mt, kt);
      Whh0[mt][kt] = ldW(dWhh0, w, l, mt, kt);
      Wih1[mt][kt] = ldW(dWih1, w, l, mt, kt);
      Whh1[mt][kt] = ldW(dWhh1, w, l, mt, kt);
    }
  const float fcwA = fcW[c0], fcwB = fcW[c0+1], fcb0 = fcb[0];

  // ---- decoder: 168 steps ----
  for (int k=0; k<84; k++){
    DEC_STEP(0, 2*k);
    DEC_STEP(1, 2*k+1);
  }
}

extern "C" void kernel_launch(void* const* d_in, const int* in_sizes, int n_in,
                              void* d_out, int out_size, void* d_ws, size_t ws_size,
                              hipStream_t stream)
{
  (void)in_sizes; (void)n_in; (void)d_ws; (void)ws_size; (void)out_size;
  const float* x     = (const float*)d_in[0];
  const float* eWih0 = (const float*)d_in[1];
  const float* eWhh0 = (const float*)d_in[2];
  const float* ebih0 = (const float*)d_in[3];
  const float* ebhh0 = (const float*)d_in[4];
  const float* eWih1 = (const float*)d_in[5];
  const float* eWhh1 = (const float*)d_in[6];
  const float* ebih1 = (const float*)d_in[7];
  const float* ebhh1 = (const float*)d_in[8];
  const float* dWih0 = (const float*)d_in[9];
  const float* dWhh0 = (const float*)d_in[10];
  const float* dbih0 = (const float*)d_in[11];
  const float* dbhh0 = (const float*)d_in[12];
  const float* dWih1 = (const float*)d_in[13];
  const float* dWhh1 = (const float*)d_in[14];
  const float* dbih1 = (const float*)d_in[15];
  const float* dbhh1 = (const float*)d_in[16];
  const float* fcW   = (const float*)d_in[17];
  const float* fcb   = (const float*)d_in[18];
  float* out = (float*)d_out;

  edlstm_kernel<<<dim3(512), dim3(NT), 0, stream>>>(
      x, eWih0, eWhh0, ebih0, ebhh0, eWih1, eWhh1, ebih1, ebhh1,
      dWih0, dWhh0, dbih0, dbhh0, dWih1, dWhh1, dbih1, dbhh1,
      fcW, fcb, out);
}